// Round 1
// baseline (394.827 us; speedup 1.0000x reference)
//
#include <hip/hip_runtime.h>
#include <math.h>

#define BB 4
#define NN 128
#define DD 256
#define KK 128
#define HH 32
#define AA 128
#define EE 512

__device__ __forceinline__ float gelu_exact(float x) {
    return 0.5f * x * (1.0f + erff(x * 0.70710678118654752f));
}

// ---------------- K0: padding mask (keep) + no_pos ----------------
__global__ void k0_masks(const float* __restrict__ pos, const int* __restrict__ x,
                         float* __restrict__ keep, float* __restrict__ no_pos) {
    int b = blockIdx.x;
    int n = threadIdx.x;
    int allz = 1;
    #pragma unroll
    for (int f = 0; f < 9; ++f) allz &= (x[(b * NN + n) * 9 + f] == 0);
    keep[b * NN + n] = allz ? 0.0f : 1.0f;

    __shared__ int flag;
    if (n == 0) flag = 0;
    __syncthreads();
    float p0 = pos[(b * NN + n) * 3 + 0];
    float p1 = pos[(b * NN + n) * 3 + 1];
    float p2 = pos[(b * NN + n) * 3 + 2];
    if (p0 != 0.0f || p1 != 0.0f || p2 != 0.0f) flag = 1;
    __syncthreads();
    if (n == 0) no_pos[b] = flag ? 1.0f : 0.0f;
}

// ---------------- K1: delta_pos (normalized, output), dist, s = sum_j keep_j*dp ----------------
__global__ void k1_geom(const float* __restrict__ pos, const float* __restrict__ keep,
                        float* __restrict__ out_dp, float* __restrict__ dist_ws,
                        float* __restrict__ s_ws) {
    int bi = blockIdx.x;            // b*N + i
    int b = bi >> 7;
    int j = threadIdx.x;
    float pix = pos[bi * 3 + 0], piy = pos[bi * 3 + 1], piz = pos[bi * 3 + 2];
    int bj = b * NN + j;
    float dx = pos[bj * 3 + 0] - pix;
    float dy = pos[bj * 3 + 1] - piy;
    float dz = pos[bj * 3 + 2] - piz;
    float dist = sqrtf(dx * dx + dy * dy + dz * dz);
    float inv = 1.0f / (dist + 1e-5f);
    dx *= inv; dy *= inv; dz *= inv;
    size_t e = (size_t)bi * NN + j;
    out_dp[e * 3 + 0] = dx;
    out_dp[e * 3 + 1] = dy;
    out_dp[e * 3 + 2] = dz;
    dist_ws[e] = dist;

    float kj = keep[bj];
    __shared__ float red[3][128];
    red[0][j] = kj * dx; red[1][j] = kj * dy; red[2][j] = kj * dz;
    __syncthreads();
    for (int off = 64; off > 0; off >>= 1) {
        if (j < off) {
            red[0][j] += red[0][j + off];
            red[1][j] += red[1][j + off];
            red[2][j] += red[2][j + off];
        }
        __syncthreads();
    }
    if (j == 0) {
        s_ws[bi * 3 + 0] = red[0][0];
        s_ws[bi * 3 + 1] = red[1][0];
        s_ws[bi * 3 + 2] = red[2][0];
    }
}

// ---------------- K2: node feature, 4 matvecs, angle MLP ----------------
__global__ __launch_bounds__(256) void k2_node(
    const float* __restrict__ atom_emb, const int* __restrict__ x,
    const float* __restrict__ W_la, const float* __restrict__ W_ra,
    const float* __restrict__ W_ld, const float* __restrict__ W_rd,
    const float* __restrict__ ang_W1, const float* __restrict__ ang_b1,
    const float* __restrict__ ang_W2, const float* __restrict__ ang_b2,
    const float* __restrict__ s_ws, const float* __restrict__ no_pos,
    float* __restrict__ ld_ws, float* __restrict__ rd_ws,
    float* __restrict__ out_angle) {
    int bn = blockIdx.x;            // b*N + n
    int b = bn >> 7;
    int t = threadIdx.x;            // feature index d'
    __shared__ float nf[DD];
    __shared__ float bufA[DD];
    __shared__ float bufB[DD];

    float acc = 0.0f;
    #pragma unroll
    for (int f = 0; f < 9; ++f) {
        int xi = x[bn * 9 + f];
        acc += atom_emb[(f * (AA + 1) + xi) * DD + t];
    }
    nf[t] = acc;
    __syncthreads();

    float la = 0.0f, ra = 0.0f, ldv = 0.0f, rdv = 0.0f;
    for (int d = 0; d < DD; ++d) {
        float v = nf[d];
        la  += v * W_la[d * DD + t];
        ra  += v * W_ra[d * DD + t];
        ldv += v * W_ld[d * DD + t];
        rdv += v * W_rd[d * DD + t];
    }
    ld_ws[bn * DD + t] = ldv;
    rd_ws[bn * DD + t] = rdv;

    float s0 = s_ws[bn * 3 + 0], s1 = s_ws[bn * 3 + 1], s2c = s_ws[bn * 3 + 2];
    float s2 = s0 * s0 + s1 * s1 + s2c * s2c;
    bufA[t] = s2 * la * ra;
    __syncthreads();

    float h = 0.0f;
    for (int d = 0; d < DD; ++d) h += bufA[d] * ang_W1[d * DD + t];
    h = gelu_exact(h + ang_b1[t]);
    bufB[t] = h;
    __syncthreads();

    float o = 0.0f;
    for (int d = 0; d < DD; ++d) o += bufB[d] * ang_W2[d * DD + t];
    o = (o + ang_b2[t]) * no_pos[b];
    out_angle[bn * DD + t] = o;
}

// ---------------- K3: per-edge gaussian + dihedral MLPs, 16 edges/block ----------------
__global__ __launch_bounds__(256) void k3_edge(
    const float* __restrict__ dih_W1, const float* __restrict__ dih_b1,
    const float* __restrict__ dih_W2, const float* __restrict__ dih_b2,
    const float* __restrict__ gbf_W1, const float* __restrict__ gbf_b1,
    const float* __restrict__ gbf_W2, const float* __restrict__ gbf_b2,
    const float* __restrict__ gbf_means, const float* __restrict__ gbf_stds,
    const float* __restrict__ src_mul, const float* __restrict__ tgt_mul,
    const float* __restrict__ src_bias, const float* __restrict__ tgt_bias,
    const int* __restrict__ nte,
    const float* __restrict__ ld_ws, const float* __restrict__ rd_ws,
    const float* __restrict__ s_ws, const float* __restrict__ dist_ws,
    const float* __restrict__ keep, const float* __restrict__ no_pos,
    const float* __restrict__ dp_in,
    float* __restrict__ out_attn) {
    const int TILE = 16;
    int blk = blockIdx.x;           // b*1024 + i*8 + jt
    int jt = blk & 7;
    int i  = (blk >> 3) & 127;
    int b  = blk >> 10;
    int j0 = jt * TILE;
    int t = threadIdx.x;

    __shared__ float sE[TILE][DD];   // dih MLP input; reused as sOut after phase C
    __shared__ float sH[TILE][DD];   // dih hidden
    __shared__ float sG[TILE][KK];   // gaussian features
    __shared__ float sGH[TILE][KK];  // gbf hidden
    __shared__ float sg[TILE];
    __shared__ float sxg[TILE];

    int bi = b * NN + i;

    // Phase A: per-edge scalars
    if (t < TILE) {
        int j = j0 + t;
        size_t e = (size_t)bi * NN + j;
        float d0 = dp_in[e * 3 + 0], d1 = dp_in[e * 3 + 1], d2 = dp_in[e * 3 + 2];
        float si0 = s_ws[bi * 3 + 0], si1 = s_ws[bi * 3 + 1], si2 = s_ws[bi * 3 + 2];
        int bj = b * NN + j;
        float sj0 = s_ws[bj * 3 + 0], sj1 = s_ws[bj * 3 + 1], sj2 = s_ws[bj * 3 + 2];
        float u = sj0 * d0 + sj1 * d1 + sj2 * d2;
        float v = si0 * d0 + si1 * d1 + si2 * d2;
        float dp2 = d0 * d0 + d1 * d1 + d2 * d2;
        sg[t] = (si0 * sj0 + si1 * sj1 + si2 * sj2) - u * v * (2.0f - dp2);
        int et0 = nte[e * 2 + 0], et1 = nte[e * 2 + 1];
        float dist = dist_ws[e];
        sxg[t] = (src_mul[et0] + tgt_mul[et1]) * dist + src_bias[et0] + tgt_bias[et1];
    }
    __syncthreads();

    // Phase B: build dih input  e[d] = g * ld[j][d] * rd[i][d]
    {
        float rdi = rd_ws[bi * DD + t];
        #pragma unroll
        for (int e = 0; e < TILE; ++e) {
            sE[e][t] = sg[e] * ld_ws[(b * NN + j0 + e) * DD + t] * rdi;
        }
    }
    // Phase E: gaussian features
    #pragma unroll
    for (int r = 0; r < 8; ++r) {
        int idx = t + r * 256;
        int e = idx >> 7, k = idx & 127;
        float std = fabsf(gbf_stds[k]) + 0.01f;
        float rr = (sxg[e] - gbf_means[k]) / std;
        sG[e][k] = expf(-0.5f * rr * rr) / (2.5066262f * std);
    }
    __syncthreads();

    // Phase C: dih W1 (256x256) + gelu -> sH
    {
        int eg = t >> 6;                 // wave id: edge group
        int c4 = (t & 63) * 4;           // 4 output columns
        float4 acc[4] = {{0,0,0,0},{0,0,0,0},{0,0,0,0},{0,0,0,0}};
        for (int d = 0; d < DD; ++d) {
            float4 w = *reinterpret_cast<const float4*>(&dih_W1[d * DD + c4]);
            #pragma unroll
            for (int k = 0; k < 4; ++k) {
                float ev = sE[eg * 4 + k][d];
                acc[k].x += ev * w.x; acc[k].y += ev * w.y;
                acc[k].z += ev * w.z; acc[k].w += ev * w.w;
            }
        }
        float4 b1v = *reinterpret_cast<const float4*>(&dih_b1[c4]);
        #pragma unroll
        for (int k = 0; k < 4; ++k) {
            float4 h;
            h.x = gelu_exact(acc[k].x + b1v.x);
            h.y = gelu_exact(acc[k].y + b1v.y);
            h.z = gelu_exact(acc[k].z + b1v.z);
            h.w = gelu_exact(acc[k].w + b1v.w);
            *reinterpret_cast<float4*>(&sH[eg * 4 + k][c4]) = h;
        }
    }
    // Phase F: gbf W1 (128x128) + gelu -> sGH
    {
        int ep = (t >> 5) * 2;
        int c4 = (t & 31) * 4;
        float4 accA = {0,0,0,0}, accB = {0,0,0,0};
        for (int d = 0; d < KK; ++d) {
            float4 w = *reinterpret_cast<const float4*>(&gbf_W1[d * KK + c4]);
            float ea = sG[ep][d], eb = sG[ep + 1][d];
            accA.x += ea * w.x; accA.y += ea * w.y; accA.z += ea * w.z; accA.w += ea * w.w;
            accB.x += eb * w.x; accB.y += eb * w.y; accB.z += eb * w.z; accB.w += eb * w.w;
        }
        float4 b1v = *reinterpret_cast<const float4*>(&gbf_b1[c4]);
        float4 hA, hB;
        hA.x = gelu_exact(accA.x + b1v.x); hA.y = gelu_exact(accA.y + b1v.y);
        hA.z = gelu_exact(accA.z + b1v.z); hA.w = gelu_exact(accA.w + b1v.w);
        hB.x = gelu_exact(accB.x + b1v.x); hB.y = gelu_exact(accB.y + b1v.y);
        hB.z = gelu_exact(accB.z + b1v.z); hB.w = gelu_exact(accB.w + b1v.w);
        *reinterpret_cast<float4*>(&sGH[ep][c4]) = hA;
        *reinterpret_cast<float4*>(&sGH[ep + 1][c4]) = hB;
    }
    __syncthreads();

    // Phase D + G: second layers (256->32 and 128->32)
    float* sOut = &sE[0][0];   // sE is dead; reuse: [0,512) dih out, [512,1024) gbf out
    {
        int hh = t & 31, e0 = t >> 5;    // e0 in 0..7, edges e0 and e0+8
        float a0 = 0.0f, a1 = 0.0f;
        for (int d = 0; d < DD; ++d) {
            float w = dih_W2[d * HH + hh];
            a0 += sH[e0][d] * w;
            a1 += sH[e0 + 8][d] * w;
        }
        float db2 = dih_b2[hh];
        float g0 = 0.0f, g1 = 0.0f;
        for (int d = 0; d < KK; ++d) {
            float w = gbf_W2[d * HH + hh];
            g0 += sGH[e0][d] * w;
            g1 += sGH[e0 + 8][d] * w;
        }
        float gb2 = gbf_b2[hh];
        sOut[e0 * 32 + hh] = a0 + db2;
        sOut[(e0 + 8) * 32 + hh] = a1 + db2;
        sOut[512 + e0 * 32 + hh] = g0 + gb2;
        sOut[512 + (e0 + 8) * 32 + hh] = g1 + gb2;
    }
    __syncthreads();

    // Phase H: combine, scale, mask, write transposed [B,H,N,N]
    float npos = no_pos[b];
    #pragma unroll
    for (int r = 0; r < 2; ++r) {
        int idx = t + r * 256;
        int hh = idx >> 4, e = idx & 15;
        float val = (sOut[e * 32 + hh] + sOut[512 + e * 32 + hh]) * npos;
        if (keep[b * NN + j0 + e] == 0.0f) val = -INFINITY;
        out_attn[(((size_t)b * HH + hh) * NN + i) * NN + (j0 + e)] = val;
    }
}

extern "C" void kernel_launch(void* const* d_in, const int* in_sizes, int n_in,
                              void* d_out, int out_size, void* d_ws, size_t ws_size,
                              hipStream_t stream) {
    const float* pos       = (const float*)d_in[0];
    const float* atom_emb  = (const float*)d_in[1];
    const float* W_la      = (const float*)d_in[2];
    const float* W_ra      = (const float*)d_in[3];
    const float* W_ld      = (const float*)d_in[4];
    const float* W_rd      = (const float*)d_in[5];
    const float* gbf_means = (const float*)d_in[6];
    const float* gbf_stds  = (const float*)d_in[7];
    const float* src_mul   = (const float*)d_in[8];
    const float* tgt_mul   = (const float*)d_in[9];
    const float* src_bias  = (const float*)d_in[10];
    const float* tgt_bias  = (const float*)d_in[11];
    const float* gbf_W1    = (const float*)d_in[12];
    const float* gbf_b1    = (const float*)d_in[13];
    const float* gbf_W2    = (const float*)d_in[14];
    const float* gbf_b2    = (const float*)d_in[15];
    const float* dih_W1    = (const float*)d_in[16];
    const float* dih_b1    = (const float*)d_in[17];
    const float* dih_W2    = (const float*)d_in[18];
    const float* dih_b2    = (const float*)d_in[19];
    const float* ang_W1    = (const float*)d_in[20];
    const float* ang_b1    = (const float*)d_in[21];
    const float* ang_W2    = (const float*)d_in[22];
    const float* ang_b2    = (const float*)d_in[23];
    const int*   x         = (const int*)d_in[24];
    const int*   nte       = (const int*)d_in[25];

    float* out = (float*)d_out;
    float* out_attn  = out;                                  // [4,32,128,128]
    float* out_angle = out + (size_t)BB * HH * NN * NN;      // [4,128,256]
    float* out_dp    = out_angle + (size_t)BB * NN * DD;     // [4,128,128,3]

    float* ws = (float*)d_ws;
    float* keep    = ws;                   // 512
    float* no_pos  = ws + 512;             // 4
    float* s_ws    = ws + 1024;            // 1536
    float* dist_ws = ws + 4096;            // 65536
    float* ld_ws   = ws + 4096 + 65536;    // 131072
    float* rd_ws   = ld_ws + (size_t)BB * NN * DD;  // 131072

    k0_masks<<<dim3(BB), dim3(NN), 0, stream>>>(pos, x, keep, no_pos);
    k1_geom<<<dim3(BB * NN), dim3(NN), 0, stream>>>(pos, keep, out_dp, dist_ws, s_ws);
    k2_node<<<dim3(BB * NN), dim3(256), 0, stream>>>(
        atom_emb, x, W_la, W_ra, W_ld, W_rd, ang_W1, ang_b1, ang_W2, ang_b2,
        s_ws, no_pos, ld_ws, rd_ws, out_angle);
    k3_edge<<<dim3(BB * NN * (NN / 16)), dim3(256), 0, stream>>>(
        dih_W1, dih_b1, dih_W2, dih_b2, gbf_W1, gbf_b1, gbf_W2, gbf_b2,
        gbf_means, gbf_stds, src_mul, tgt_mul, src_bias, tgt_bias, nte,
        ld_ws, rd_ws, s_ws, dist_ws, keep, no_pos, out_dp, out_attn);
}

// Round 2
// 213.878 us; speedup vs baseline: 1.8460x; 1.8460x over previous
//
#include <hip/hip_runtime.h>
#include <math.h>

#define BB 4
#define NN 128
#define DD 256
#define KK 128
#define HH 32
#define AA 128
#define EE 512

typedef float f32x4 __attribute__((ext_vector_type(4)));
typedef short short8 __attribute__((ext_vector_type(8)));

__device__ __forceinline__ float gelu_exact(float x) {
    return 0.5f * x * (1.0f + erff(x * 0.70710678118654752f));
}

__device__ __forceinline__ unsigned short f2bf(float f) {
    unsigned int u = __float_as_uint(f);
    u = u + 0x7fffu + ((u >> 16) & 1u);
    return (unsigned short)(u >> 16);
}

// ---------------- K0: padding mask (keep) + no_pos ----------------
__global__ void k0_masks(const float* __restrict__ pos, const int* __restrict__ x,
                         float* __restrict__ keep, float* __restrict__ no_pos) {
    int b = blockIdx.x;
    int n = threadIdx.x;
    int allz = 1;
    #pragma unroll
    for (int f = 0; f < 9; ++f) allz &= (x[(b * NN + n) * 9 + f] == 0);
    keep[b * NN + n] = allz ? 0.0f : 1.0f;

    __shared__ int flag;
    if (n == 0) flag = 0;
    __syncthreads();
    float p0 = pos[(b * NN + n) * 3 + 0];
    float p1 = pos[(b * NN + n) * 3 + 1];
    float p2 = pos[(b * NN + n) * 3 + 2];
    if (p0 != 0.0f || p1 != 0.0f || p2 != 0.0f) flag = 1;
    __syncthreads();
    if (n == 0) no_pos[b] = flag ? 1.0f : 0.0f;
}

// ---------------- K1: delta_pos (normalized, output), dist, s ----------------
__global__ void k1_geom(const float* __restrict__ pos, const float* __restrict__ keep,
                        float* __restrict__ out_dp, float* __restrict__ dist_ws,
                        float* __restrict__ s_ws) {
    int bi = blockIdx.x;            // b*N + i
    int b = bi >> 7;
    int j = threadIdx.x;
    float pix = pos[bi * 3 + 0], piy = pos[bi * 3 + 1], piz = pos[bi * 3 + 2];
    int bj = b * NN + j;
    float dx = pos[bj * 3 + 0] - pix;
    float dy = pos[bj * 3 + 1] - piy;
    float dz = pos[bj * 3 + 2] - piz;
    float dist = sqrtf(dx * dx + dy * dy + dz * dz);
    float inv = 1.0f / (dist + 1e-5f);
    dx *= inv; dy *= inv; dz *= inv;
    size_t e = (size_t)bi * NN + j;
    out_dp[e * 3 + 0] = dx;
    out_dp[e * 3 + 1] = dy;
    out_dp[e * 3 + 2] = dz;
    dist_ws[e] = dist;

    float kj = keep[bj];
    __shared__ float red[3][128];
    red[0][j] = kj * dx; red[1][j] = kj * dy; red[2][j] = kj * dz;
    __syncthreads();
    for (int off = 64; off > 0; off >>= 1) {
        if (j < off) {
            red[0][j] += red[0][j + off];
            red[1][j] += red[1][j + off];
            red[2][j] += red[2][j + off];
        }
        __syncthreads();
    }
    if (j == 0) {
        s_ws[bi * 3 + 0] = red[0][0];
        s_ws[bi * 3 + 1] = red[1][0];
        s_ws[bi * 3 + 2] = red[2][0];
    }
}

// ---------------- K2: node feature, 4 matvecs, angle MLP ----------------
__global__ __launch_bounds__(256) void k2_node(
    const float* __restrict__ atom_emb, const int* __restrict__ x,
    const float* __restrict__ W_la, const float* __restrict__ W_ra,
    const float* __restrict__ W_ld, const float* __restrict__ W_rd,
    const float* __restrict__ ang_W1, const float* __restrict__ ang_b1,
    const float* __restrict__ ang_W2, const float* __restrict__ ang_b2,
    const float* __restrict__ s_ws, const float* __restrict__ no_pos,
    float* __restrict__ ld_ws, float* __restrict__ rd_ws,
    float* __restrict__ out_angle) {
    int bn = blockIdx.x;            // b*N + n
    int b = bn >> 7;
    int t = threadIdx.x;            // feature index d'
    __shared__ float nf[DD];
    __shared__ float bufA[DD];
    __shared__ float bufB[DD];

    float acc = 0.0f;
    #pragma unroll
    for (int f = 0; f < 9; ++f) {
        int xi = x[bn * 9 + f];
        acc += atom_emb[(f * (AA + 1) + xi) * DD + t];
    }
    nf[t] = acc;
    __syncthreads();

    float la = 0.0f, ra = 0.0f, ldv = 0.0f, rdv = 0.0f;
    for (int d = 0; d < DD; ++d) {
        float v = nf[d];
        la  += v * W_la[d * DD + t];
        ra  += v * W_ra[d * DD + t];
        ldv += v * W_ld[d * DD + t];
        rdv += v * W_rd[d * DD + t];
    }
    ld_ws[bn * DD + t] = ldv;
    rd_ws[bn * DD + t] = rdv;

    float s0 = s_ws[bn * 3 + 0], s1 = s_ws[bn * 3 + 1], s2c = s_ws[bn * 3 + 2];
    float s2 = s0 * s0 + s1 * s1 + s2c * s2c;
    bufA[t] = s2 * la * ra;
    __syncthreads();

    float h = 0.0f;
    for (int d = 0; d < DD; ++d) h += bufA[d] * ang_W1[d * DD + t];
    h = gelu_exact(h + ang_b1[t]);
    bufB[t] = h;
    __syncthreads();

    float o = 0.0f;
    for (int d = 0; d < DD; ++d) o += bufB[d] * ang_W2[d * DD + t];
    o = (o + ang_b2[t]) * no_pos[b];
    out_angle[bn * DD + t] = o;
}

// ---------------- K_pack: weights -> bf16 MFMA B-fragment layout ----------------
// Wp[((ks*ntiles + nt)*64 + l)*8 + e] = bf16( W[ks*32 + (l>>4)*8 + e][nt*16 + (l&15)] )
__global__ void k_pack(const float* __restrict__ dW1, const float* __restrict__ dW2,
                       const float* __restrict__ gW1, const float* __restrict__ gW2,
                       unsigned short* __restrict__ out) {
    int idx = blockIdx.x * 256 + threadIdx.x;   // 0..94207
    const float* W; int Nc; int local; int base;
    if (idx < 65536)       { W = dW1; Nc = 256; local = idx;          base = 0; }
    else if (idx < 73728)  { W = dW2; Nc = 32;  local = idx - 65536;  base = 65536; }
    else if (idx < 90112)  { W = gW1; Nc = 128; local = idx - 73728;  base = 73728; }
    else if (idx < 94208)  { W = gW2; Nc = 32;  local = idx - 90112;  base = 90112; }
    else return;
    int ntiles = Nc >> 4;
    int e = local & 7;
    int l = (local >> 3) & 63;
    int rr = local >> 9;
    int nt = rr % ntiles;
    int ks = rr / ntiles;
    int k = ks * 32 + ((l >> 4) & 3) * 8 + e;
    int c = nt * 16 + (l & 15);
    out[base + local] = f2bf(W[k * Nc + c]);
}

// ---------------- K3: MFMA edge kernel, 64 edges/block, 4 waves ----------------
__global__ __launch_bounds__(256, 4) void k3_mfma(
    const unsigned short* __restrict__ Wp1, const unsigned short* __restrict__ Wp2,
    const unsigned short* __restrict__ Wg1, const unsigned short* __restrict__ Wg2,
    const float* __restrict__ dih_b1, const float* __restrict__ dih_b2,
    const float* __restrict__ gbf_b1, const float* __restrict__ gbf_b2,
    const float* __restrict__ gbf_means, const float* __restrict__ gbf_stds,
    const float* __restrict__ src_mul, const float* __restrict__ tgt_mul,
    const float* __restrict__ src_bias, const float* __restrict__ tgt_bias,
    const int* __restrict__ nte,
    const float* __restrict__ ld_ws, const float* __restrict__ rd_ws,
    const float* __restrict__ s_ws, const float* __restrict__ dist_ws,
    const float* __restrict__ keep, const float* __restrict__ no_pos,
    const float* __restrict__ dp_in,
    float* __restrict__ out_attn) {
    int blk = blockIdx.x;           // b*256 + i*2 + jh
    int jh = blk & 1;
    int i  = (blk >> 1) & 127;
    int b  = blk >> 8;
    int j0 = jh * 64;
    int t = threadIdx.x;
    int w  = t >> 6;                // wave id 0..3
    int l  = t & 63;
    int lo = l & 15;
    int hi = l >> 4;

    __shared__ unsigned short sHbuf[64 * 264];   // H [64][264]; later aliased HG [64][136]
    __shared__ float sg[64], sxg[64], skeep[64];
    __shared__ float lmean[KK], linv[KK], lcoef[KK];

    int bi = b * NN + i;

    // ---- phase A: per-edge scalars + gaussian constants ----
    if (t < 64) {
        int j = j0 + t;
        size_t e = (size_t)bi * NN + j;
        float d0 = dp_in[e * 3 + 0], d1 = dp_in[e * 3 + 1], d2 = dp_in[e * 3 + 2];
        float si0 = s_ws[bi * 3 + 0], si1 = s_ws[bi * 3 + 1], si2 = s_ws[bi * 3 + 2];
        int bj = b * NN + j;
        float sj0 = s_ws[bj * 3 + 0], sj1 = s_ws[bj * 3 + 1], sj2 = s_ws[bj * 3 + 2];
        float u = sj0 * d0 + sj1 * d1 + sj2 * d2;
        float v = si0 * d0 + si1 * d1 + si2 * d2;
        float dp2 = d0 * d0 + d1 * d1 + d2 * d2;
        sg[t] = (si0 * sj0 + si1 * sj1 + si2 * sj2) - u * v * (2.0f - dp2);
        int et0 = nte[e * 2 + 0], et1 = nte[e * 2 + 1];
        sxg[t] = (src_mul[et0] + tgt_mul[et1]) * dist_ws[e] + src_bias[et0] + tgt_bias[et1];
        skeep[t] = keep[bj];
    }
    if (t >= 128) {
        int k = t - 128;
        float s = fabsf(gbf_stds[k]) + 0.01f;
        lmean[k] = gbf_means[k];
        linv[k] = 1.0f / s;
        lcoef[k] = 1.0f / (2.5066262f * s);
    }
    __syncthreads();

    // ---- GEMM1 dih: E[64x256] @ W1[256x256], E built in registers ----
    f32x4 acc[4][4] = {};
    const float* rdrow = &rd_ws[(size_t)bi * DD];
    for (int ks = 0; ks < 8; ++ks) {
        int k0 = ks * 32 + hi * 8;
        float4 r0 = *reinterpret_cast<const float4*>(&rdrow[k0]);
        float4 r1 = *reinterpret_cast<const float4*>(&rdrow[k0 + 4]);
        short8 afr[4];
        #pragma unroll
        for (int m = 0; m < 4; ++m) {
            int row = m * 16 + lo;
            const float* ldr = &ld_ws[((size_t)(b * NN + j0 + row)) * DD + k0];
            float4 l0 = *reinterpret_cast<const float4*>(ldr);
            float4 l1 = *reinterpret_cast<const float4*>(ldr + 4);
            float gv = sg[row];
            short8 a;
            a[0] = (short)f2bf(gv * l0.x * r0.x);
            a[1] = (short)f2bf(gv * l0.y * r0.y);
            a[2] = (short)f2bf(gv * l0.z * r0.z);
            a[3] = (short)f2bf(gv * l0.w * r0.w);
            a[4] = (short)f2bf(gv * l1.x * r1.x);
            a[5] = (short)f2bf(gv * l1.y * r1.y);
            a[6] = (short)f2bf(gv * l1.z * r1.z);
            a[7] = (short)f2bf(gv * l1.w * r1.w);
            afr[m] = a;
        }
        #pragma unroll
        for (int n = 0; n < 4; ++n) {
            short8 bfr = *reinterpret_cast<const short8*>(&Wp1[(((size_t)ks * 16 + (w * 4 + n)) * 64 + l) * 8]);
            #pragma unroll
            for (int m = 0; m < 4; ++m)
                acc[m][n] = __builtin_amdgcn_mfma_f32_16x16x32_bf16(afr[m], bfr, acc[m][n], 0, 0, 0);
        }
    }
    // gelu + write H to LDS (bf16, stride 264)
    {
        #pragma unroll
        for (int n = 0; n < 4; ++n) {
            float b1v = dih_b1[w * 64 + n * 16 + lo];
            int col = w * 64 + n * 16 + lo;
            #pragma unroll
            for (int m = 0; m < 4; ++m) {
                int row0 = m * 16 + hi * 4;
                #pragma unroll
                for (int r = 0; r < 4; ++r)
                    sHbuf[(row0 + r) * 264 + col] = f2bf(gelu_exact(acc[m][n][r] + b1v));
            }
        }
    }
    __syncthreads();

    // ---- GEMM2 dih: H[64x256] @ W2[256x32], wave w owns m-tile w ----
    f32x4 acc2d[2] = {};
    for (int ks = 0; ks < 8; ++ks) {
        short8 a = *reinterpret_cast<const short8*>(&sHbuf[(w * 16 + lo) * 264 + ks * 32 + hi * 8]);
        #pragma unroll
        for (int n = 0; n < 2; ++n) {
            short8 bfr = *reinterpret_cast<const short8*>(&Wp2[(((size_t)ks * 2 + n) * 64 + l) * 8]);
            acc2d[n] = __builtin_amdgcn_mfma_f32_16x16x32_bf16(a, bfr, acc2d[n], 0, 0, 0);
        }
    }

    // ---- GEMM1 gbf: G[64x128] @ Wg1[128x128], G built analytically ----
    f32x4 accg[4][2] = {};
    for (int ks = 0; ks < 4; ++ks) {
        int k0 = ks * 32 + hi * 8;
        float4 m0 = *reinterpret_cast<const float4*>(&lmean[k0]);
        float4 m1 = *reinterpret_cast<const float4*>(&lmean[k0 + 4]);
        float4 i0 = *reinterpret_cast<const float4*>(&linv[k0]);
        float4 i1 = *reinterpret_cast<const float4*>(&linv[k0 + 4]);
        float4 c0 = *reinterpret_cast<const float4*>(&lcoef[k0]);
        float4 c1 = *reinterpret_cast<const float4*>(&lcoef[k0 + 4]);
        short8 afr[4];
        #pragma unroll
        for (int m = 0; m < 4; ++m) {
            float xv = sxg[m * 16 + lo];
            float z;
            short8 a;
            z = (xv - m0.x) * i0.x; a[0] = (short)f2bf(c0.x * __expf(-0.5f * z * z));
            z = (xv - m0.y) * i0.y; a[1] = (short)f2bf(c0.y * __expf(-0.5f * z * z));
            z = (xv - m0.z) * i0.z; a[2] = (short)f2bf(c0.z * __expf(-0.5f * z * z));
            z = (xv - m0.w) * i0.w; a[3] = (short)f2bf(c0.w * __expf(-0.5f * z * z));
            z = (xv - m1.x) * i1.x; a[4] = (short)f2bf(c1.x * __expf(-0.5f * z * z));
            z = (xv - m1.y) * i1.y; a[5] = (short)f2bf(c1.y * __expf(-0.5f * z * z));
            z = (xv - m1.z) * i1.z; a[6] = (short)f2bf(c1.z * __expf(-0.5f * z * z));
            z = (xv - m1.w) * i1.w; a[7] = (short)f2bf(c1.w * __expf(-0.5f * z * z));
            afr[m] = a;
        }
        #pragma unroll
        for (int n = 0; n < 2; ++n) {
            short8 bfr = *reinterpret_cast<const short8*>(&Wg1[(((size_t)ks * 8 + (w * 2 + n)) * 64 + l) * 8]);
            #pragma unroll
            for (int m = 0; m < 4; ++m)
                accg[m][n] = __builtin_amdgcn_mfma_f32_16x16x32_bf16(afr[m], bfr, accg[m][n], 0, 0, 0);
        }
    }
    __syncthreads();   // everyone done reading H; safe to alias with HG

    // gelu + write HG to LDS (bf16, stride 136)
    {
        #pragma unroll
        for (int n = 0; n < 2; ++n) {
            float b1v = gbf_b1[w * 32 + n * 16 + lo];
            int col = w * 32 + n * 16 + lo;
            #pragma unroll
            for (int m = 0; m < 4; ++m) {
                int row0 = m * 16 + hi * 4;
                #pragma unroll
                for (int r = 0; r < 4; ++r)
                    sHbuf[(row0 + r) * 136 + col] = f2bf(gelu_exact(accg[m][n][r] + b1v));
            }
        }
    }
    __syncthreads();

    // ---- GEMM2 gbf: HG[64x128] @ Wg2[128x32] ----
    f32x4 acc2g[2] = {};
    for (int ks = 0; ks < 4; ++ks) {
        short8 a = *reinterpret_cast<const short8*>(&sHbuf[(w * 16 + lo) * 136 + ks * 32 + hi * 8]);
        #pragma unroll
        for (int n = 0; n < 2; ++n) {
            short8 bfr = *reinterpret_cast<const short8*>(&Wg2[(((size_t)ks * 2 + n) * 64 + l) * 8]);
            acc2g[n] = __builtin_amdgcn_mfma_f32_16x16x32_bf16(a, bfr, acc2g[n], 0, 0, 0);
        }
    }

    // ---- epilogue: combine, bias, scale, mask, store float4 ----
    float npos = no_pos[b];
    int e0 = w * 16 + hi * 4;
    #pragma unroll
    for (int n = 0; n < 2; ++n) {
        int h = n * 16 + lo;
        float bsum = dih_b2[h] + gbf_b2[h];
        float4 v;
        float vr;
        vr = (acc2d[n][0] + acc2g[n][0] + bsum) * npos; v.x = (skeep[e0 + 0] == 0.0f) ? -INFINITY : vr;
        vr = (acc2d[n][1] + acc2g[n][1] + bsum) * npos; v.y = (skeep[e0 + 1] == 0.0f) ? -INFINITY : vr;
        vr = (acc2d[n][2] + acc2g[n][2] + bsum) * npos; v.z = (skeep[e0 + 2] == 0.0f) ? -INFINITY : vr;
        vr = (acc2d[n][3] + acc2g[n][3] + bsum) * npos; v.w = (skeep[e0 + 3] == 0.0f) ? -INFINITY : vr;
        *reinterpret_cast<float4*>(&out_attn[(((size_t)b * HH + h) * NN + i) * NN + j0 + e0]) = v;
    }
}

extern "C" void kernel_launch(void* const* d_in, const int* in_sizes, int n_in,
                              void* d_out, int out_size, void* d_ws, size_t ws_size,
                              hipStream_t stream) {
    const float* pos       = (const float*)d_in[0];
    const float* atom_emb  = (const float*)d_in[1];
    const float* W_la      = (const float*)d_in[2];
    const float* W_ra      = (const float*)d_in[3];
    const float* W_ld      = (const float*)d_in[4];
    const float* W_rd      = (const float*)d_in[5];
    const float* gbf_means = (const float*)d_in[6];
    const float* gbf_stds  = (const float*)d_in[7];
    const float* src_mul   = (const float*)d_in[8];
    const float* tgt_mul   = (const float*)d_in[9];
    const float* src_bias  = (const float*)d_in[10];
    const float* tgt_bias  = (const float*)d_in[11];
    const float* gbf_W1    = (const float*)d_in[12];
    const float* gbf_b1    = (const float*)d_in[13];
    const float* gbf_W2    = (const float*)d_in[14];
    const float* gbf_b2    = (const float*)d_in[15];
    const float* dih_W1    = (const float*)d_in[16];
    const float* dih_b1    = (const float*)d_in[17];
    const float* dih_W2    = (const float*)d_in[18];
    const float* dih_b2    = (const float*)d_in[19];
    const float* ang_W1    = (const float*)d_in[20];
    const float* ang_b1    = (const float*)d_in[21];
    const float* ang_W2    = (const float*)d_in[22];
    const float* ang_b2    = (const float*)d_in[23];
    const int*   x         = (const int*)d_in[24];
    const int*   nte       = (const int*)d_in[25];

    float* out = (float*)d_out;
    float* out_attn  = out;                                  // [4,32,128,128]
    float* out_angle = out + (size_t)BB * HH * NN * NN;      // [4,128,256]
    float* out_dp    = out_angle + (size_t)BB * NN * DD;     // [4,128,128,3]

    float* ws = (float*)d_ws;
    float* keep    = ws;                       // 512
    float* no_pos  = ws + 512;                 // 4
    float* s_ws    = ws + 1024;                // 1536
    float* dist_ws = ws + 4096;                // 65536
    float* ld_ws   = ws + 4096 + 65536;        // 131072
    float* rd_ws   = ld_ws + (size_t)BB * NN * DD;   // 131072
    unsigned short* wp = (unsigned short*)(ws + 331776);
    unsigned short* Wp1 = wp;            // 65536
    unsigned short* Wp2 = wp + 65536;    // 8192
    unsigned short* Wg1 = wp + 73728;    // 16384
    unsigned short* Wg2 = wp + 90112;    // 4096

    k0_masks<<<dim3(BB), dim3(NN), 0, stream>>>(pos, x, keep, no_pos);
    k1_geom<<<dim3(BB * NN), dim3(NN), 0, stream>>>(pos, keep, out_dp, dist_ws, s_ws);
    k_pack<<<dim3(368), dim3(256), 0, stream>>>(dih_W1, dih_W2, gbf_W1, gbf_W2, wp);
    k2_node<<<dim3(BB * NN), dim3(256), 0, stream>>>(
        atom_emb, x, W_la, W_ra, W_ld, W_rd, ang_W1, ang_b1, ang_W2, ang_b2,
        s_ws, no_pos, ld_ws, rd_ws, out_angle);
    k3_mfma<<<dim3(BB * NN * 2), dim3(256), 0, stream>>>(
        Wp1, Wp2, Wg1, Wg2, dih_b1, dih_b2, gbf_b1, gbf_b2,
        gbf_means, gbf_stds, src_mul, tgt_mul, src_bias, tgt_bias, nte,
        ld_ws, rd_ws, s_ws, dist_ws, keep, no_pos, out_dp, out_attn);
}

// Round 6
// 200.761 us; speedup vs baseline: 1.9666x; 1.0653x over previous
//
#include <hip/hip_runtime.h>
#include <math.h>

#define BB 4
#define NN 128
#define DD 256
#define KK 128
#define HH 32
#define AA 128
#define EE 512

typedef float f32x4 __attribute__((ext_vector_type(4)));
typedef short short8 __attribute__((ext_vector_type(8)));

__device__ __forceinline__ float gelu_exact(float x) {
    return 0.5f * x * (1.0f + erff(x * 0.70710678118654752f));
}

// tanh-form GELU: x * sigmoid(2*0.7978845608*(x + 0.044715 x^3)); |err| <= ~3e-4
__device__ __forceinline__ float gelu_fast(float x) {
    float x2 = x * x;
    float t = x * fmaf(x2, 0.0713548162726f, 1.59576912161f);
    float e = __expf(-t);
    return x * __builtin_amdgcn_rcpf(1.0f + e);
}

__device__ __forceinline__ unsigned short f2bf(float f) {
    unsigned int u = __float_as_uint(f);
    u = u + 0x7fffu + ((u >> 16) & 1u);
    return (unsigned short)(u >> 16);
}

// byte-offset swizzles (XOR row into 16B-slot bit) for bank-conflict-free ds_read_b128
__device__ __forceinline__ int swz512(int row, int colByte) {   // 512B row stride
    return row * 512 + (colByte ^ ((row & 7) << 4));
}
__device__ __forceinline__ int swz256(int row, int colByte) {   // 256B row stride
    return row * 256 + (colByte ^ ((row & 7) << 4));
}

// ---------------- K1: masks + delta_pos + dist + s ----------------
__global__ void k1_geom(const float* __restrict__ pos, const int* __restrict__ x,
                        float* __restrict__ out_dp, float* __restrict__ dist_ws,
                        float* __restrict__ s_ws, float* __restrict__ keep,
                        float* __restrict__ no_pos) {
    int bi = blockIdx.x;            // b*N + i
    int b = bi >> 7;
    int i = bi & 127;
    int j = threadIdx.x;
    int bj = b * NN + j;

    int allz = 1;
    #pragma unroll
    for (int f = 0; f < 9; ++f) allz &= (x[bj * 9 + f] == 0);
    float kj = allz ? 0.0f : 1.0f;

    __shared__ int flag;
    if (j == 0) flag = 0;

    float pix = pos[bi * 3 + 0], piy = pos[bi * 3 + 1], piz = pos[bi * 3 + 2];
    float pjx = pos[bj * 3 + 0], pjy = pos[bj * 3 + 1], pjz = pos[bj * 3 + 2];
    float dx = pjx - pix, dy = pjy - piy, dz = pjz - piz;
    float dist = sqrtf(dx * dx + dy * dy + dz * dz);
    float inv = 1.0f / (dist + 1e-5f);
    dx *= inv; dy *= inv; dz *= inv;
    size_t e = (size_t)bi * NN + j;
    out_dp[e * 3 + 0] = dx;
    out_dp[e * 3 + 1] = dy;
    out_dp[e * 3 + 2] = dz;
    dist_ws[e] = dist;

    __shared__ float red[3][128];
    red[0][j] = kj * dx; red[1][j] = kj * dy; red[2][j] = kj * dz;
    __syncthreads();
    if (pjx != 0.0f || pjy != 0.0f || pjz != 0.0f) flag = 1;
    for (int off = 64; off > 0; off >>= 1) {
        if (j < off) {
            red[0][j] += red[0][j + off];
            red[1][j] += red[1][j + off];
            red[2][j] += red[2][j + off];
        }
        __syncthreads();
    }
    if (j == 0) {
        s_ws[bi * 3 + 0] = red[0][0];
        s_ws[bi * 3 + 1] = red[1][0];
        s_ws[bi * 3 + 2] = red[2][0];
    }
    if (i == 0) {
        keep[bj] = kj;
        if (j == 0) no_pos[b] = flag ? 1.0f : 0.0f;
    }
}

// ---------------- K2: node feature, 4 matvecs, angle MLP ----------------
__global__ __launch_bounds__(256) void k2_node(
    const float* __restrict__ atom_emb, const int* __restrict__ x,
    const float* __restrict__ W_la, const float* __restrict__ W_ra,
    const float* __restrict__ W_ld, const float* __restrict__ W_rd,
    const float* __restrict__ ang_W1, const float* __restrict__ ang_b1,
    const float* __restrict__ ang_W2, const float* __restrict__ ang_b2,
    const float* __restrict__ s_ws, const float* __restrict__ no_pos,
    float* __restrict__ ld_ws, float* __restrict__ rd_ws,
    float* __restrict__ out_angle) {
    int bn = blockIdx.x;            // b*N + n
    int b = bn >> 7;
    int t = threadIdx.x;            // feature index d'
    __shared__ float nf[DD];
    __shared__ float bufA[DD];
    __shared__ float bufB[DD];

    float acc = 0.0f;
    #pragma unroll
    for (int f = 0; f < 9; ++f) {
        int xi = x[bn * 9 + f];
        acc += atom_emb[(f * (AA + 1) + xi) * DD + t];
    }
    nf[t] = acc;
    __syncthreads();

    float la = 0.0f, ra = 0.0f, ldv = 0.0f, rdv = 0.0f;
    #pragma unroll 4
    for (int d = 0; d < DD; ++d) {
        float v = nf[d];
        la  += v * W_la[d * DD + t];
        ra  += v * W_ra[d * DD + t];
        ldv += v * W_ld[d * DD + t];
        rdv += v * W_rd[d * DD + t];
    }
    ld_ws[bn * DD + t] = ldv;
    rd_ws[bn * DD + t] = rdv;

    float s0 = s_ws[bn * 3 + 0], s1 = s_ws[bn * 3 + 1], s2c = s_ws[bn * 3 + 2];
    float s2 = s0 * s0 + s1 * s1 + s2c * s2c;
    bufA[t] = s2 * la * ra;
    __syncthreads();

    float h = 0.0f;
    #pragma unroll 4
    for (int d = 0; d < DD; ++d) h += bufA[d] * ang_W1[d * DD + t];
    h = gelu_exact(h + ang_b1[t]);
    bufB[t] = h;
    __syncthreads();

    float o = 0.0f;
    #pragma unroll 4
    for (int d = 0; d < DD; ++d) o += bufB[d] * ang_W2[d * DD + t];
    o = (o + ang_b2[t]) * no_pos[b];
    out_angle[bn * DD + t] = o;
}

// ---------------- K_pack: weights -> bf16 MFMA B-fragment layout (coalesced reads) ----------------
// Wp[((ks*ntiles + nt)*64 + l)*8 + e] = bf16( W[ks*32 + (l>>4)*8 + e][nt*16 + (l&15)] )
__global__ void k_pack(const float* __restrict__ dW1, const float* __restrict__ dW2,
                       const float* __restrict__ gW1, const float* __restrict__ gW2,
                       unsigned short* __restrict__ out) {
    int idx = blockIdx.x * 256 + threadIdx.x;   // 0..11775  (one thread = 8 consecutive cols of one row)
    const float* W; int Nc, base, k, c8;
    if (idx < 8192)       { W = dW1; Nc = 256; base = 0;     int li = idx;         k = li >> 5; c8 = li & 31; }
    else if (idx < 9216)  { W = dW2; Nc = 32;  base = 65536; int li = idx - 8192;  k = li >> 2; c8 = li & 3; }
    else if (idx < 11264) { W = gW1; Nc = 128; base = 73728; int li = idx - 9216;  k = li >> 4; c8 = li & 15; }
    else if (idx < 11776) { W = gW2; Nc = 32;  base = 90112; int li = idx - 11264; k = li >> 2; c8 = li & 3; }
    else return;
    int ntiles = Nc >> 4;
    int ks = k >> 5, hi = (k & 31) >> 3, ee = k & 7;
    const float* wp = &W[k * Nc + c8 * 8];
    float4 a = *reinterpret_cast<const float4*>(wp);
    float4 b4 = *reinterpret_cast<const float4*>(wp + 4);
    float vals[8] = {a.x, a.y, a.z, a.w, b4.x, b4.y, b4.z, b4.w};
    #pragma unroll
    for (int jj = 0; jj < 8; ++jj) {
        int c = c8 * 8 + jj;
        int nt = c >> 4, lo = c & 15;
        out[base + (((ks * ntiles + nt) * 64) + hi * 16 + lo) * 8 + ee] = f2bf(vals[jj]);
    }
}

// ---------------- K3: MFMA edge kernel, 64 edges/block, 4 waves, staged A ----------------
__global__ __launch_bounds__(256, 2) void k3_mfma(
    const unsigned short* __restrict__ Wp1, const unsigned short* __restrict__ Wp2,
    const unsigned short* __restrict__ Wg1, const unsigned short* __restrict__ Wg2,
    const float* __restrict__ dih_b1, const float* __restrict__ dih_b2,
    const float* __restrict__ gbf_b1, const float* __restrict__ gbf_b2,
    const float* __restrict__ gbf_means, const float* __restrict__ gbf_stds,
    const float* __restrict__ src_mul, const float* __restrict__ tgt_mul,
    const float* __restrict__ src_bias, const float* __restrict__ tgt_bias,
    const int* __restrict__ nte,
    const float* __restrict__ ld_ws, const float* __restrict__ rd_ws,
    const float* __restrict__ s_ws, const float* __restrict__ dist_ws,
    const float* __restrict__ keep, const float* __restrict__ no_pos,
    const float* __restrict__ dp_in,
    float* __restrict__ out_attn) {
    int blk = blockIdx.x;           // b*256 + i*2 + jh
    int jh = blk & 1;
    int i  = (blk >> 1) & 127;
    int b  = blk >> 8;
    int j0 = jh * 64;
    int t = threadIdx.x;
    int w  = t >> 6;                // wave id 0..3
    int l  = t & 63;
    int lo = l & 15;
    int hi = l >> 4;

    __shared__ __align__(16) unsigned short sE[64 * 256];   // E bf16 swizzled; later aliased by sGH [64][128]
    __shared__ __align__(16) unsigned short sH[64 * 256];   // first 16KB holds sG before H is written
    __shared__ __align__(16) float rd_l[DD];
    __shared__ float sg[64], sxg[64], skeep[64];
    __shared__ __align__(16) float lmean[KK], linv[KK], lcoef[KK];

    int bi = b * NN + i;

    // ---- phase A: per-edge scalars + rd row + gaussian constants ----
    if (t < 64) {
        int j = j0 + t;
        size_t e = (size_t)bi * NN + j;
        float d0 = dp_in[e * 3 + 0], d1 = dp_in[e * 3 + 1], d2 = dp_in[e * 3 + 2];
        float si0 = s_ws[bi * 3 + 0], si1 = s_ws[bi * 3 + 1], si2 = s_ws[bi * 3 + 2];
        int bj = b * NN + j;
        float sj0 = s_ws[bj * 3 + 0], sj1 = s_ws[bj * 3 + 1], sj2 = s_ws[bj * 3 + 2];
        float u = sj0 * d0 + sj1 * d1 + sj2 * d2;
        float v = si0 * d0 + si1 * d1 + si2 * d2;
        float dp2 = d0 * d0 + d1 * d1 + d2 * d2;
        sg[t] = (si0 * sj0 + si1 * sj1 + si2 * sj2) - u * v * (2.0f - dp2);
        int et0 = nte[e * 2 + 0], et1 = nte[e * 2 + 1];
        sxg[t] = (src_mul[et0] + tgt_mul[et1]) * dist_ws[e] + src_bias[et0] + tgt_bias[et1];
        skeep[t] = keep[bj];
    } else if (t < 128) {
        int q = t - 64;
        reinterpret_cast<float4*>(rd_l)[q] =
            reinterpret_cast<const float4*>(&rd_ws[(size_t)bi * DD])[q];
    } else {
        int k = t - 128;
        float s = fabsf(gbf_stds[k]) + 0.01f;
        lmean[k] = gbf_means[k];
        linv[k] = 1.0f / s;
        lcoef[k] = 1.0f / (2.5066262f * s);
    }
    __syncthreads();

    // ---- phase B: build E (bf16, swizzled) and G (bf16, swizzled, inside sH) once ----
    {
        const float* ldbase = &ld_ws[((size_t)(b * NN + j0)) * DD];
        #pragma unroll
        for (int r = 0; r < 8; ++r) {
            int idx = r * 256 + t;
            int row = idx >> 5;          // 0..63
            int c8  = idx & 31;
            float g = sg[row];
            const float* lp = ldbase + row * DD + c8 * 8;
            float4 l0 = *reinterpret_cast<const float4*>(lp);
            float4 l1 = *reinterpret_cast<const float4*>(lp + 4);
            float4 r0 = *reinterpret_cast<const float4*>(&rd_l[c8 * 8]);
            float4 r1 = *reinterpret_cast<const float4*>(&rd_l[c8 * 8 + 4]);
            short8 vv;
            vv[0] = (short)f2bf(g * l0.x * r0.x);
            vv[1] = (short)f2bf(g * l0.y * r0.y);
            vv[2] = (short)f2bf(g * l0.z * r0.z);
            vv[3] = (short)f2bf(g * l0.w * r0.w);
            vv[4] = (short)f2bf(g * l1.x * r1.x);
            vv[5] = (short)f2bf(g * l1.y * r1.y);
            vv[6] = (short)f2bf(g * l1.z * r1.z);
            vv[7] = (short)f2bf(g * l1.w * r1.w);
            *reinterpret_cast<short8*>((char*)sE + swz512(row, c8 * 16)) = vv;
        }
        unsigned short* sG = sH;   // G lives in sH until H overwrites it (after sync)
        #pragma unroll
        for (int r = 0; r < 4; ++r) {
            int idx = r * 256 + t;
            int row = idx >> 4;          // 0..63
            int c8  = idx & 15;
            float xv = sxg[row];
            float4 m0 = *reinterpret_cast<const float4*>(&lmean[c8 * 8]);
            float4 m1 = *reinterpret_cast<const float4*>(&lmean[c8 * 8 + 4]);
            float4 i0 = *reinterpret_cast<const float4*>(&linv[c8 * 8]);
            float4 i1 = *reinterpret_cast<const float4*>(&linv[c8 * 8 + 4]);
            float4 c0 = *reinterpret_cast<const float4*>(&lcoef[c8 * 8]);
            float4 c1 = *reinterpret_cast<const float4*>(&lcoef[c8 * 8 + 4]);
            float z;
            short8 vv;
            z = (xv - m0.x) * i0.x; vv[0] = (short)f2bf(c0.x * __expf(-0.5f * z * z));
            z = (xv - m0.y) * i0.y; vv[1] = (short)f2bf(c0.y * __expf(-0.5f * z * z));
            z = (xv - m0.z) * i0.z; vv[2] = (short)f2bf(c0.z * __expf(-0.5f * z * z));
            z = (xv - m0.w) * i0.w; vv[3] = (short)f2bf(c0.w * __expf(-0.5f * z * z));
            z = (xv - m1.x) * i1.x; vv[4] = (short)f2bf(c1.x * __expf(-0.5f * z * z));
            z = (xv - m1.y) * i1.y; vv[5] = (short)f2bf(c1.y * __expf(-0.5f * z * z));
            z = (xv - m1.z) * i1.z; vv[6] = (short)f2bf(c1.z * __expf(-0.5f * z * z));
            z = (xv - m1.w) * i1.w; vv[7] = (short)f2bf(c1.w * __expf(-0.5f * z * z));
            *reinterpret_cast<short8*>((char*)sG + swz256(row, c8 * 16)) = vv;
        }
    }
    __syncthreads();

    // ---- phase C: GEMM1-gbf (reads sG) and GEMM1-dih (reads sE); no LDS writes ----
    f32x4 accg[4][2] = {};
    {
        const unsigned short* sG = sH;
        for (int ks = 0; ks < 4; ++ks) {
            short8 a[4];
            #pragma unroll
            for (int m = 0; m < 4; ++m)
                a[m] = *reinterpret_cast<const short8*>((const char*)sG + swz256(m * 16 + lo, ks * 64 + hi * 16));
            #pragma unroll
            for (int n = 0; n < 2; ++n) {
                short8 bfr = *reinterpret_cast<const short8*>(&Wg1[(((size_t)ks * 8 + (w * 2 + n)) * 64 + l) * 8]);
                #pragma unroll
                for (int m = 0; m < 4; ++m)
                    accg[m][n] = __builtin_amdgcn_mfma_f32_16x16x32_bf16(a[m], bfr, accg[m][n], 0, 0, 0);
            }
        }
    }
    f32x4 acc[4][4] = {};
    for (int ks = 0; ks < 8; ++ks) {
        short8 a[4];
        #pragma unroll
        for (int m = 0; m < 4; ++m)
            a[m] = *reinterpret_cast<const short8*>((const char*)sE + swz512(m * 16 + lo, ks * 64 + hi * 16));
        #pragma unroll
        for (int n = 0; n < 4; ++n) {
            short8 bfr = *reinterpret_cast<const short8*>(&Wp1[(((size_t)ks * 16 + (w * 4 + n)) * 64 + l) * 8]);
            #pragma unroll
            for (int m = 0; m < 4; ++m)
                acc[m][n] = __builtin_amdgcn_mfma_f32_16x16x32_bf16(a[m], bfr, acc[m][n], 0, 0, 0);
        }
    }
    __syncthreads();

    // ---- phase D: gelu + write H (sH) and HG (alias over sE) ----
    {
        #pragma unroll
        for (int n = 0; n < 4; ++n) {
            int col = w * 64 + n * 16 + lo;
            float b1v = dih_b1[col];
            #pragma unroll
            for (int m = 0; m < 4; ++m) {
                int row0 = m * 16 + hi * 4;
                #pragma unroll
                for (int r = 0; r < 4; ++r) {
                    *reinterpret_cast<unsigned short*>((char*)sH + swz512(row0 + r, col * 2)) =
                        f2bf(gelu_fast(acc[m][n][r] + b1v));
                }
            }
        }
        unsigned short* sGH = sE;   // sE dead
        #pragma unroll
        for (int n = 0; n < 2; ++n) {
            int col = w * 32 + n * 16 + lo;
            float b1v = gbf_b1[col];
            #pragma unroll
            for (int m = 0; m < 4; ++m) {
                int row0 = m * 16 + hi * 4;
                #pragma unroll
                for (int r = 0; r < 4; ++r) {
                    *reinterpret_cast<unsigned short*>((char*)sGH + swz256(row0 + r, col * 2)) =
                        f2bf(gelu_fast(accg[m][n][r] + b1v));
                }
            }
        }
    }
    __syncthreads();

    // ---- phase E: GEMM2-dih + GEMM2-gbf + epilogue ----
    f32x4 acc2d[2] = {};
    for (int ks = 0; ks < 8; ++ks) {
        short8 a = *reinterpret_cast<const short8*>((const char*)sH + swz512(w * 16 + lo, ks * 64 + hi * 16));
        #pragma unroll
        for (int n = 0; n < 2; ++n) {
            short8 bfr = *reinterpret_cast<const short8*>(&Wp2[(((size_t)ks * 2 + n) * 64 + l) * 8]);
            acc2d[n] = __builtin_amdgcn_mfma_f32_16x16x32_bf16(a, bfr, acc2d[n], 0, 0, 0);
        }
    }
    f32x4 acc2g[2] = {};
    {
        const unsigned short* sGH = sE;
        for (int ks = 0; ks < 4; ++ks) {
            short8 a = *reinterpret_cast<const short8*>((const char*)sGH + swz256(w * 16 + lo, ks * 64 + hi * 16));
            #pragma unroll
            for (int n = 0; n < 2; ++n) {
                short8 bfr = *reinterpret_cast<const short8*>(&Wg2[(((size_t)ks * 2 + n) * 64 + l) * 8]);
                acc2g[n] = __builtin_amdgcn_mfma_f32_16x16x32_bf16(a, bfr, acc2g[n], 0, 0, 0);
            }
        }
    }

    float npos = no_pos[b];
    int e0 = w * 16 + hi * 4;
    #pragma unroll
    for (int n = 0; n < 2; ++n) {
        int h = n * 16 + lo;
        float bsum = dih_b2[h] + gbf_b2[h];
        float4 v;
        float vr;
        vr = (acc2d[n][0] + acc2g[n][0] + bsum) * npos; v.x = (skeep[e0 + 0] == 0.0f) ? -INFINITY : vr;
        vr = (acc2d[n][1] + acc2g[n][1] + bsum) * npos; v.y = (skeep[e0 + 1] == 0.0f) ? -INFINITY : vr;
        vr = (acc2d[n][2] + acc2g[n][2] + bsum) * npos; v.z = (skeep[e0 + 2] == 0.0f) ? -INFINITY : vr;
        vr = (acc2d[n][3] + acc2g[n][3] + bsum) * npos; v.w = (skeep[e0 + 3] == 0.0f) ? -INFINITY : vr;
        *reinterpret_cast<float4*>(&out_attn[(((size_t)b * HH + h) * NN + i) * NN + j0 + e0]) = v;
    }
}

extern "C" void kernel_launch(void* const* d_in, const int* in_sizes, int n_in,
                              void* d_out, int out_size, void* d_ws, size_t ws_size,
                              hipStream_t stream) {
    const float* pos       = (const float*)d_in[0];
    const float* atom_emb  = (const float*)d_in[1];
    const float* W_la      = (const float*)d_in[2];
    const float* W_ra      = (const float*)d_in[3];
    const float* W_ld      = (const float*)d_in[4];
    const float* W_rd      = (const float*)d_in[5];
    const float* gbf_means = (const float*)d_in[6];
    const float* gbf_stds  = (const float*)d_in[7];
    const float* src_mul   = (const float*)d_in[8];
    const float* tgt_mul   = (const float*)d_in[9];
    const float* src_bias  = (const float*)d_in[10];
    const float* tgt_bias  = (const float*)d_in[11];
    const float* gbf_W1    = (const float*)d_in[12];
    const float* gbf_b1    = (const float*)d_in[13];
    const float* gbf_W2    = (const float*)d_in[14];
    const float* gbf_b2    = (const float*)d_in[15];
    const float* dih_W1    = (const float*)d_in[16];
    const float* dih_b1    = (const float*)d_in[17];
    const float* dih_W2    = (const float*)d_in[18];
    const float* dih_b2    = (const float*)d_in[19];
    const float* ang_W1    = (const float*)d_in[20];
    const float* ang_b1    = (const float*)d_in[21];
    const float* ang_W2    = (const float*)d_in[22];
    const float* ang_b2    = (const float*)d_in[23];
    const int*   x         = (const int*)d_in[24];
    const int*   nte       = (const int*)d_in[25];

    float* out = (float*)d_out;
    float* out_attn  = out;                                  // [4,32,128,128]
    float* out_angle = out + (size_t)BB * HH * NN * NN;      // [4,128,256]
    float* out_dp    = out_angle + (size_t)BB * NN * DD;     // [4,128,128,3]

    float* ws = (float*)d_ws;
    float* keep    = ws;                       // 512
    float* no_pos  = ws + 512;                 // 4
    float* s_ws    = ws + 1024;                // 1536
    float* dist_ws = ws + 4096;                // 65536
    float* ld_ws   = ws + 4096 + 65536;        // 131072
    float* rd_ws   = ld_ws + (size_t)BB * NN * DD;   // 131072
    unsigned short* wp = (unsigned short*)(ws + 331776);
    unsigned short* Wp1 = wp;            // 65536
    unsigned short* Wp2 = wp + 65536;    // 8192
    unsigned short* Wg1 = wp + 73728;    // 16384
    unsigned short* Wg2 = wp + 90112;    // 4096

    k1_geom<<<dim3(BB * NN), dim3(NN), 0, stream>>>(pos, x, out_dp, dist_ws, s_ws, keep, no_pos);
    k_pack<<<dim3(46), dim3(256), 0, stream>>>(dih_W1, dih_W2, gbf_W1, gbf_W2, wp);
    k2_node<<<dim3(BB * NN), dim3(256), 0, stream>>>(
        atom_emb, x, W_la, W_ra, W_ld, W_rd, ang_W1, ang_b1, ang_W2, ang_b2,
        s_ws, no_pos, ld_ws, rd_ws, out_angle);
    k3_mfma<<<dim3(BB * NN * 2), dim3(256), 0, stream>>>(
        Wp1, Wp2, Wg1, Wg2, dih_b1, dih_b2, gbf_b1, gbf_b2,
        gbf_means, gbf_stds, src_mul, tgt_mul, src_bias, tgt_bias, nte,
        ld_ws, rd_ws, s_ws, dist_ws, keep, no_pos, out_dp, out_attn);
}

// Round 7
// 196.014 us; speedup vs baseline: 2.0143x; 1.0242x over previous
//
#include <hip/hip_runtime.h>
#include <math.h>

#define BB 4
#define NN 128
#define DD 256
#define KK 128
#define HH 32
#define AA 128
#define EE 512

typedef float f32x4 __attribute__((ext_vector_type(4)));
typedef short short8 __attribute__((ext_vector_type(8)));
typedef unsigned short ushort4v __attribute__((ext_vector_type(4)));

// tanh-form GELU: x * sigmoid(2*0.7978845608*(x + 0.044715 x^3)); |err| <= ~3e-4
__device__ __forceinline__ float gelu_fast(float x) {
    float x2 = x * x;
    float t = x * fmaf(x2, 0.0713548162726f, 1.59576912161f);
    float e = __expf(-t);
    return x * __builtin_amdgcn_rcpf(1.0f + e);
}

__device__ __forceinline__ unsigned short f2bf(float f) {
    unsigned int u = __float_as_uint(f);
    u = u + 0x7fffu + ((u >> 16) & 1u);
    return (unsigned short)(u >> 16);
}

// byte-offset swizzles (XOR row into 16B-slot bit) for bank-conflict-free ds_read_b128
__device__ __forceinline__ int swz512(int row, int colByte) {   // 512B row stride
    return row * 512 + (colByte ^ ((row & 7) << 4));
}
__device__ __forceinline__ int swz256(int row, int colByte) {   // 256B row stride
    return row * 256 + (colByte ^ ((row & 7) << 4));
}

// ---------------- K1: masks + delta_pos + dist + s ----------------
__global__ void k1_geom(const float* __restrict__ pos, const int* __restrict__ x,
                        float* __restrict__ out_dp, float* __restrict__ dist_ws,
                        float* __restrict__ s_ws, float* __restrict__ keep,
                        float* __restrict__ no_pos) {
    int bi = blockIdx.x;            // b*N + i
    int b = bi >> 7;
    int i = bi & 127;
    int j = threadIdx.x;
    int bj = b * NN + j;

    int allz = 1;
    #pragma unroll
    for (int f = 0; f < 9; ++f) allz &= (x[bj * 9 + f] == 0);
    float kj = allz ? 0.0f : 1.0f;

    __shared__ int flag;
    if (j == 0) flag = 0;

    float pix = pos[bi * 3 + 0], piy = pos[bi * 3 + 1], piz = pos[bi * 3 + 2];
    float pjx = pos[bj * 3 + 0], pjy = pos[bj * 3 + 1], pjz = pos[bj * 3 + 2];
    float dx = pjx - pix, dy = pjy - piy, dz = pjz - piz;
    float dist = sqrtf(dx * dx + dy * dy + dz * dz);
    float inv = 1.0f / (dist + 1e-5f);
    dx *= inv; dy *= inv; dz *= inv;
    size_t e = (size_t)bi * NN + j;
    out_dp[e * 3 + 0] = dx;
    out_dp[e * 3 + 1] = dy;
    out_dp[e * 3 + 2] = dz;
    dist_ws[e] = dist;

    __shared__ float red[3][128];
    red[0][j] = kj * dx; red[1][j] = kj * dy; red[2][j] = kj * dz;
    __syncthreads();
    if (pjx != 0.0f || pjy != 0.0f || pjz != 0.0f) flag = 1;
    for (int off = 64; off > 0; off >>= 1) {
        if (j < off) {
            red[0][j] += red[0][j + off];
            red[1][j] += red[1][j + off];
            red[2][j] += red[2][j + off];
        }
        __syncthreads();
    }
    if (j == 0) {
        s_ws[bi * 3 + 0] = red[0][0];
        s_ws[bi * 3 + 1] = red[1][0];
        s_ws[bi * 3 + 2] = red[2][0];
    }
    if (i == 0) {
        keep[bj] = kj;
        if (j == 0) no_pos[b] = flag ? 1.0f : 0.0f;
    }
}

// ---------------- K_pack: weights -> bf16 MFMA B-fragment layout (coalesced reads) ----------------
// Wp[((ks*ntiles + nt)*64 + l)*8 + e] = bf16( W[ks*32 + (l>>4)*8 + e][nt*16 + (l&15)] )
__global__ void k_pack(const float* __restrict__ dW1, const float* __restrict__ dW2,
                       const float* __restrict__ gW1, const float* __restrict__ gW2,
                       const float* __restrict__ wla, const float* __restrict__ wra,
                       const float* __restrict__ wld, const float* __restrict__ wrd,
                       const float* __restrict__ aW1, const float* __restrict__ aW2,
                       unsigned short* __restrict__ out) {
    int idx = blockIdx.x * 256 + threadIdx.x;   // 0..60927 (one thread = 8 consecutive cols of one row)
    const float* W; int Nc, base, k, c8;
    if (idx < 8192)       { W = dW1; Nc = 256; base = 0;     int li = idx;         k = li >> 5; c8 = li & 31; }
    else if (idx < 9216)  { W = dW2; Nc = 32;  base = 65536; int li = idx - 8192;  k = li >> 2; c8 = li & 3; }
    else if (idx < 11264) { W = gW1; Nc = 128; base = 73728; int li = idx - 9216;  k = li >> 4; c8 = li & 15; }
    else if (idx < 11776) { W = gW2; Nc = 32;  base = 90112; int li = idx - 11264; k = li >> 2; c8 = li & 3; }
    else if (idx < 60928) {
        int q  = (idx - 11776) >> 13;        // 0..5
        int li = (idx - 11776) & 8191;
        W = (q == 0) ? wla : (q == 1) ? wra : (q == 2) ? wld : (q == 3) ? wrd : (q == 4) ? aW1 : aW2;
        Nc = 256; base = 94208 + q * 65536; k = li >> 5; c8 = li & 31;
    }
    else return;
    int ntiles = Nc >> 4;
    int ks = k >> 5, hi = (k & 31) >> 3, ee = k & 7;
    const float* wp = &W[k * Nc + c8 * 8];
    float4 a = *reinterpret_cast<const float4*>(wp);
    float4 b4 = *reinterpret_cast<const float4*>(wp + 4);
    float vals[8] = {a.x, a.y, a.z, a.w, b4.x, b4.y, b4.z, b4.w};
    #pragma unroll
    for (int jj = 0; jj < 8; ++jj) {
        int c = c8 * 8 + jj;
        int nt = c >> 4, lo = c & 15;
        out[base + (((ks * ntiles + nt) * 64) + hi * 16 + lo) * 8 + ee] = f2bf(vals[jj]);
    }
}

// ---- helper: [32 x 256] @ [256 x 256] chunk GEMM, wave w owns cols w*64..w*64+63 ----
__device__ __forceinline__ void gemm_chunk32(const unsigned short* __restrict__ Bp,
                                             const unsigned short* sAp,
                                             int w, int l, int lo, int hi,
                                             f32x4 acc[2][4]) {
    for (int ks = 0; ks < 8; ++ks) {
        short8 a[2];
        #pragma unroll
        for (int m = 0; m < 2; ++m)
            a[m] = *reinterpret_cast<const short8*>((const char*)sAp + swz512(m * 16 + lo, ks * 64 + hi * 16));
        #pragma unroll
        for (int n = 0; n < 4; ++n) {
            short8 bfr = *reinterpret_cast<const short8*>(&Bp[(((size_t)ks * 16 + (w * 4 + n)) * 64 + l) * 8]);
            #pragma unroll
            for (int m = 0; m < 2; ++m)
                acc[m][n] = __builtin_amdgcn_mfma_f32_16x16x32_bf16(a[m], bfr, acc[m][n], 0, 0, 0);
        }
    }
}

// ---------------- K2: MFMA node kernel — embeddings, 4 projections, angle MLP ----------------
// 16 blocks x 32 nodes, 4 waves. All GEMMs via MFMA with packed bf16 weights.
__global__ __launch_bounds__(256, 2) void k2_mfma(
    const float* __restrict__ atom_emb, const int* __restrict__ x,
    const unsigned short* __restrict__ Wla_p, const unsigned short* __restrict__ Wra_p,
    const unsigned short* __restrict__ Wld_p, const unsigned short* __restrict__ Wrd_p,
    const unsigned short* __restrict__ WaW1_p, const unsigned short* __restrict__ WaW2_p,
    const float* __restrict__ ang_b1, const float* __restrict__ ang_b2,
    const float* __restrict__ s_ws, const float* __restrict__ no_pos,
    float* __restrict__ ld_ws, float* __restrict__ rd_ws,
    float* __restrict__ out_angle) {
    int blk = blockIdx.x;          // 16 blocks; 32 nodes each
    int bn0 = blk * 32;
    int b = blk >> 2;              // 4 blocks per batch
    int t = threadIdx.x;
    int w = t >> 6, l = t & 63, lo = l & 15, hi = l >> 4;

    __shared__ __align__(16) unsigned short sA[32 * 256];  // nf, then angle_pre (bf16 swizzled)
    __shared__ __align__(16) unsigned short sB[32 * 256];  // gelu hidden (bf16 swizzled)
    __shared__ float ls2[32];
    __shared__ float lnp;

    // ---- phase A: embedding sum -> nf (bf16, swizzled); s2; no_pos ----
    if (t < 32) {
        float a0 = s_ws[(bn0 + t) * 3 + 0];
        float a1 = s_ws[(bn0 + t) * 3 + 1];
        float a2 = s_ws[(bn0 + t) * 3 + 2];
        ls2[t] = a0 * a0 + a1 * a1 + a2 * a2;
        if (t == 0) lnp = no_pos[b];
    }
    #pragma unroll
    for (int r8 = 0; r8 < 8; ++r8) {
        int row = w * 8 + r8;
        int bn = bn0 + row;
        float4 accv = {0.0f, 0.0f, 0.0f, 0.0f};
        #pragma unroll
        for (int f = 0; f < 9; ++f) {
            int xi = x[bn * 9 + f];
            float4 vv = *reinterpret_cast<const float4*>(&atom_emb[((size_t)(f * (AA + 1) + xi)) * DD + l * 4]);
            accv.x += vv.x; accv.y += vv.y; accv.z += vv.z; accv.w += vv.w;
        }
        ushort4v uv;
        uv[0] = f2bf(accv.x); uv[1] = f2bf(accv.y); uv[2] = f2bf(accv.z); uv[3] = f2bf(accv.w);
        *reinterpret_cast<ushort4v*>((char*)sA + swz512(row, l * 8)) = uv;
    }
    __syncthreads();

    // ---- GEMM1: la, ra (kept), ld, rd (stored) ----
    f32x4 a_la[2][4] = {}, a_ra[2][4] = {};
    gemm_chunk32(Wla_p, sA, w, l, lo, hi, a_la);
    gemm_chunk32(Wra_p, sA, w, l, lo, hi, a_ra);
    {
        f32x4 acc[2][4] = {};
        gemm_chunk32(Wld_p, sA, w, l, lo, hi, acc);
        #pragma unroll
        for (int m = 0; m < 2; ++m)
            #pragma unroll
            for (int n = 0; n < 4; ++n)
                #pragma unroll
                for (int r = 0; r < 4; ++r)
                    ld_ws[(size_t)(bn0 + m * 16 + hi * 4 + r) * DD + w * 64 + n * 16 + lo] = acc[m][n][r];
    }
    {
        f32x4 acc[2][4] = {};
        gemm_chunk32(Wrd_p, sA, w, l, lo, hi, acc);
        #pragma unroll
        for (int m = 0; m < 2; ++m)
            #pragma unroll
            for (int n = 0; n < 4; ++n)
                #pragma unroll
                for (int r = 0; r < 4; ++r)
                    rd_ws[(size_t)(bn0 + m * 16 + hi * 4 + r) * DD + w * 64 + n * 16 + lo] = acc[m][n][r];
    }
    __syncthreads();   // all nf reads done; sA reusable

    // ---- angle_pre = s2 * la * ra -> sA (bf16, swizzled) ----
    {
        float s2v[2][4];
        #pragma unroll
        for (int m = 0; m < 2; ++m)
            #pragma unroll
            for (int r = 0; r < 4; ++r)
                s2v[m][r] = ls2[m * 16 + hi * 4 + r];
        #pragma unroll
        for (int m = 0; m < 2; ++m)
            #pragma unroll
            for (int n = 0; n < 4; ++n)
                #pragma unroll
                for (int r = 0; r < 4; ++r) {
                    int row = m * 16 + hi * 4 + r, col = w * 64 + n * 16 + lo;
                    *reinterpret_cast<unsigned short*>((char*)sA + swz512(row, col * 2)) =
                        f2bf(s2v[m][r] * a_la[m][n][r] * a_ra[m][n][r]);
                }
    }
    __syncthreads();

    // ---- angle MLP layer 1 + gelu -> sB ----
    {
        f32x4 acc[2][4] = {};
        gemm_chunk32(WaW1_p, sA, w, l, lo, hi, acc);
        #pragma unroll
        for (int n = 0; n < 4; ++n) {
            int col = w * 64 + n * 16 + lo;
            float b1v = ang_b1[col];
            #pragma unroll
            for (int m = 0; m < 2; ++m)
                #pragma unroll
                for (int r = 0; r < 4; ++r) {
                    int row = m * 16 + hi * 4 + r;
                    *reinterpret_cast<unsigned short*>((char*)sB + swz512(row, col * 2)) =
                        f2bf(gelu_fast(acc[m][n][r] + b1v));
                }
        }
    }
    __syncthreads();

    // ---- angle MLP layer 2 + bias + no_pos -> out_angle ----
    {
        f32x4 acc[2][4] = {};
        gemm_chunk32(WaW2_p, sB, w, l, lo, hi, acc);
        #pragma unroll
        for (int n = 0; n < 4; ++n) {
            int col = w * 64 + n * 16 + lo;
            float b2v = ang_b2[col];
            #pragma unroll
            for (int m = 0; m < 2; ++m)
                #pragma unroll
                for (int r = 0; r < 4; ++r) {
                    int row = m * 16 + hi * 4 + r;
                    out_angle[(size_t)(bn0 + row) * DD + col] = (acc[m][n][r] + b2v) * lnp;
                }
        }
    }
}

// ---------------- K3: MFMA edge kernel, 64 edges/block, 4 waves, staged A ----------------
__global__ __launch_bounds__(256, 2) void k3_mfma(
    const unsigned short* __restrict__ Wp1, const unsigned short* __restrict__ Wp2,
    const unsigned short* __restrict__ Wg1, const unsigned short* __restrict__ Wg2,
    const float* __restrict__ dih_b1, const float* __restrict__ dih_b2,
    const float* __restrict__ gbf_b1, const float* __restrict__ gbf_b2,
    const float* __restrict__ gbf_means, const float* __restrict__ gbf_stds,
    const float* __restrict__ src_mul, const float* __restrict__ tgt_mul,
    const float* __restrict__ src_bias, const float* __restrict__ tgt_bias,
    const int* __restrict__ nte,
    const float* __restrict__ ld_ws, const float* __restrict__ rd_ws,
    const float* __restrict__ s_ws, const float* __restrict__ dist_ws,
    const float* __restrict__ keep, const float* __restrict__ no_pos,
    const float* __restrict__ dp_in,
    float* __restrict__ out_attn) {
    int blk = blockIdx.x;           // b*256 + i*2 + jh
    int jh = blk & 1;
    int i  = (blk >> 1) & 127;
    int b  = blk >> 8;
    int j0 = jh * 64;
    int t = threadIdx.x;
    int w  = t >> 6;                // wave id 0..3
    int l  = t & 63;
    int lo = l & 15;
    int hi = l >> 4;

    __shared__ __align__(16) unsigned short sE[64 * 256];   // E bf16 swizzled; later aliased by sGH [64][128]
    __shared__ __align__(16) unsigned short sH[64 * 256];   // first 16KB holds sG before H is written
    __shared__ __align__(16) float rd_l[DD];
    __shared__ float sg[64], sxg[64], skeep[64];
    __shared__ __align__(16) float lmean[KK], linv[KK], lcoef[KK];

    int bi = b * NN + i;

    // ---- phase A: per-edge scalars + rd row + gaussian constants ----
    if (t < 64) {
        int j = j0 + t;
        size_t e = (size_t)bi * NN + j;
        float d0 = dp_in[e * 3 + 0], d1 = dp_in[e * 3 + 1], d2 = dp_in[e * 3 + 2];
        float si0 = s_ws[bi * 3 + 0], si1 = s_ws[bi * 3 + 1], si2 = s_ws[bi * 3 + 2];
        int bj = b * NN + j;
        float sj0 = s_ws[bj * 3 + 0], sj1 = s_ws[bj * 3 + 1], sj2 = s_ws[bj * 3 + 2];
        float u = sj0 * d0 + sj1 * d1 + sj2 * d2;
        float v = si0 * d0 + si1 * d1 + si2 * d2;
        float dp2 = d0 * d0 + d1 * d1 + d2 * d2;
        sg[t] = (si0 * sj0 + si1 * sj1 + si2 * sj2) - u * v * (2.0f - dp2);
        int et0 = nte[e * 2 + 0], et1 = nte[e * 2 + 1];
        sxg[t] = (src_mul[et0] + tgt_mul[et1]) * dist_ws[e] + src_bias[et0] + tgt_bias[et1];
        skeep[t] = keep[bj];
    } else if (t < 128) {
        int q = t - 64;
        reinterpret_cast<float4*>(rd_l)[q] =
            reinterpret_cast<const float4*>(&rd_ws[(size_t)bi * DD])[q];
    } else {
        int k = t - 128;
        float s = fabsf(gbf_stds[k]) + 0.01f;
        lmean[k] = gbf_means[k];
        linv[k] = 1.0f / s;
        lcoef[k] = 1.0f / (2.5066262f * s);
    }
    __syncthreads();

    // ---- phase B: build E (bf16, swizzled) and G (bf16, swizzled, inside sH) once ----
    {
        const float* ldbase = &ld_ws[((size_t)(b * NN + j0)) * DD];
        #pragma unroll
        for (int r = 0; r < 8; ++r) {
            int idx = r * 256 + t;
            int row = idx >> 5;          // 0..63
            int c8  = idx & 31;
            float g = sg[row];
            const float* lp = ldbase + row * DD + c8 * 8;
            float4 l0 = *reinterpret_cast<const float4*>(lp);
            float4 l1 = *reinterpret_cast<const float4*>(lp + 4);
            float4 r0 = *reinterpret_cast<const float4*>(&rd_l[c8 * 8]);
            float4 r1 = *reinterpret_cast<const float4*>(&rd_l[c8 * 8 + 4]);
            short8 vv;
            vv[0] = (short)f2bf(g * l0.x * r0.x);
            vv[1] = (short)f2bf(g * l0.y * r0.y);
            vv[2] = (short)f2bf(g * l0.z * r0.z);
            vv[3] = (short)f2bf(g * l0.w * r0.w);
            vv[4] = (short)f2bf(g * l1.x * r1.x);
            vv[5] = (short)f2bf(g * l1.y * r1.y);
            vv[6] = (short)f2bf(g * l1.z * r1.z);
            vv[7] = (short)f2bf(g * l1.w * r1.w);
            *reinterpret_cast<short8*>((char*)sE + swz512(row, c8 * 16)) = vv;
        }
        unsigned short* sG = sH;   // G lives in sH until H overwrites it (after sync)
        #pragma unroll
        for (int r = 0; r < 4; ++r) {
            int idx = r * 256 + t;
            int row = idx >> 4;          // 0..63
            int c8  = idx & 15;
            float xv = sxg[row];
            float4 m0 = *reinterpret_cast<const float4*>(&lmean[c8 * 8]);
            float4 m1 = *reinterpret_cast<const float4*>(&lmean[c8 * 8 + 4]);
            float4 i0 = *reinterpret_cast<const float4*>(&linv[c8 * 8]);
            float4 i1 = *reinterpret_cast<const float4*>(&linv[c8 * 8 + 4]);
            float4 c0 = *reinterpret_cast<const float4*>(&lcoef[c8 * 8]);
            float4 c1 = *reinterpret_cast<const float4*>(&lcoef[c8 * 8 + 4]);
            float z;
            short8 vv;
            z = (xv - m0.x) * i0.x; vv[0] = (short)f2bf(c0.x * __expf(-0.5f * z * z));
            z = (xv - m0.y) * i0.y; vv[1] = (short)f2bf(c0.y * __expf(-0.5f * z * z));
            z = (xv - m0.z) * i0.z; vv[2] = (short)f2bf(c0.z * __expf(-0.5f * z * z));
            z = (xv - m0.w) * i0.w; vv[3] = (short)f2bf(c0.w * __expf(-0.5f * z * z));
            z = (xv - m1.x) * i1.x; vv[4] = (short)f2bf(c1.x * __expf(-0.5f * z * z));
            z = (xv - m1.y) * i1.y; vv[5] = (short)f2bf(c1.y * __expf(-0.5f * z * z));
            z = (xv - m1.z) * i1.z; vv[6] = (short)f2bf(c1.z * __expf(-0.5f * z * z));
            z = (xv - m1.w) * i1.w; vv[7] = (short)f2bf(c1.w * __expf(-0.5f * z * z));
            *reinterpret_cast<short8*>((char*)sG + swz256(row, c8 * 16)) = vv;
        }
    }
    __syncthreads();

    // ---- phase C: GEMM1-gbf (reads sG) and GEMM1-dih (reads sE); no LDS writes ----
    f32x4 accg[4][2] = {};
    {
        const unsigned short* sG = sH;
        for (int ks = 0; ks < 4; ++ks) {
            short8 a[4];
            #pragma unroll
            for (int m = 0; m < 4; ++m)
                a[m] = *reinterpret_cast<const short8*>((const char*)sG + swz256(m * 16 + lo, ks * 64 + hi * 16));
            #pragma unroll
            for (int n = 0; n < 2; ++n) {
                short8 bfr = *reinterpret_cast<const short8*>(&Wg1[(((size_t)ks * 8 + (w * 2 + n)) * 64 + l) * 8]);
                #pragma unroll
                for (int m = 0; m < 4; ++m)
                    accg[m][n] = __builtin_amdgcn_mfma_f32_16x16x32_bf16(a[m], bfr, accg[m][n], 0, 0, 0);
            }
        }
    }
    f32x4 acc[4][4] = {};
    for (int ks = 0; ks < 8; ++ks) {
        short8 a[4];
        #pragma unroll
        for (int m = 0; m < 4; ++m)
            a[m] = *reinterpret_cast<const short8*>((const char*)sE + swz512(m * 16 + lo, ks * 64 + hi * 16));
        #pragma unroll
        for (int n = 0; n < 4; ++n) {
            short8 bfr = *reinterpret_cast<const short8*>(&Wp1[(((size_t)ks * 16 + (w * 4 + n)) * 64 + l) * 8]);
            #pragma unroll
            for (int m = 0; m < 4; ++m)
                acc[m][n] = __builtin_amdgcn_mfma_f32_16x16x32_bf16(a[m], bfr, acc[m][n], 0, 0, 0);
        }
    }
    __syncthreads();

    // ---- phase D: gelu + write H (sH) and HG (alias over sE) ----
    {
        #pragma unroll
        for (int n = 0; n < 4; ++n) {
            int col = w * 64 + n * 16 + lo;
            float b1v = dih_b1[col];
            #pragma unroll
            for (int m = 0; m < 4; ++m) {
                int row0 = m * 16 + hi * 4;
                #pragma unroll
                for (int r = 0; r < 4; ++r) {
                    *reinterpret_cast<unsigned short*>((char*)sH + swz512(row0 + r, col * 2)) =
                        f2bf(gelu_fast(acc[m][n][r] + b1v));
                }
            }
        }
        unsigned short* sGH = sE;   // sE dead
        #pragma unroll
        for (int n = 0; n < 2; ++n) {
            int col = w * 32 + n * 16 + lo;
            float b1v = gbf_b1[col];
            #pragma unroll
            for (int m = 0; m < 4; ++m) {
                int row0 = m * 16 + hi * 4;
                #pragma unroll
                for (int r = 0; r < 4; ++r) {
                    *reinterpret_cast<unsigned short*>((char*)sGH + swz256(row0 + r, col * 2)) =
                        f2bf(gelu_fast(accg[m][n][r] + b1v));
                }
            }
        }
    }
    __syncthreads();

    // ---- phase E: GEMM2-dih + GEMM2-gbf + epilogue ----
    f32x4 acc2d[2] = {};
    for (int ks = 0; ks < 8; ++ks) {
        short8 a = *reinterpret_cast<const short8*>((const char*)sH + swz512(w * 16 + lo, ks * 64 + hi * 16));
        #pragma unroll
        for (int n = 0; n < 2; ++n) {
            short8 bfr = *reinterpret_cast<const short8*>(&Wp2[(((size_t)ks * 2 + n) * 64 + l) * 8]);
            acc2d[n] = __builtin_amdgcn_mfma_f32_16x16x32_bf16(a, bfr, acc2d[n], 0, 0, 0);
        }
    }
    f32x4 acc2g[2] = {};
    {
        const unsigned short* sGH = sE;
        for (int ks = 0; ks < 4; ++ks) {
            short8 a = *reinterpret_cast<const short8*>((const char*)sGH + swz256(w * 16 + lo, ks * 64 + hi * 16));
            #pragma unroll
            for (int n = 0; n < 2; ++n) {
                short8 bfr = *reinterpret_cast<const short8*>(&Wg2[(((size_t)ks * 2 + n) * 64 + l) * 8]);
                acc2g[n] = __builtin_amdgcn_mfma_f32_16x16x32_bf16(a, bfr, acc2g[n], 0, 0, 0);
            }
        }
    }

    float npos = no_pos[b];
    int e0 = w * 16 + hi * 4;
    #pragma unroll
    for (int n = 0; n < 2; ++n) {
        int h = n * 16 + lo;
        float bsum = dih_b2[h] + gbf_b2[h];
        float4 v;
        float vr;
        vr = (acc2d[n][0] + acc2g[n][0] + bsum) * npos; v.x = (skeep[e0 + 0] == 0.0f) ? -INFINITY : vr;
        vr = (acc2d[n][1] + acc2g[n][1] + bsum) * npos; v.y = (skeep[e0 + 1] == 0.0f) ? -INFINITY : vr;
        vr = (acc2d[n][2] + acc2g[n][2] + bsum) * npos; v.z = (skeep[e0 + 2] == 0.0f) ? -INFINITY : vr;
        vr = (acc2d[n][3] + acc2g[n][3] + bsum) * npos; v.w = (skeep[e0 + 3] == 0.0f) ? -INFINITY : vr;
        *reinterpret_cast<float4*>(&out_attn[(((size_t)b * HH + h) * NN + i) * NN + j0 + e0]) = v;
    }
}

extern "C" void kernel_launch(void* const* d_in, const int* in_sizes, int n_in,
                              void* d_out, int out_size, void* d_ws, size_t ws_size,
                              hipStream_t stream) {
    const float* pos       = (const float*)d_in[0];
    const float* atom_emb  = (const float*)d_in[1];
    const float* W_la      = (const float*)d_in[2];
    const float* W_ra      = (const float*)d_in[3];
    const float* W_ld      = (const float*)d_in[4];
    const float* W_rd      = (const float*)d_in[5];
    const float* gbf_means = (const float*)d_in[6];
    const float* gbf_stds  = (const float*)d_in[7];
    const float* src_mul   = (const float*)d_in[8];
    const float* tgt_mul   = (const float*)d_in[9];
    const float* src_bias  = (const float*)d_in[10];
    const float* tgt_bias  = (const float*)d_in[11];
    const float* gbf_W1    = (const float*)d_in[12];
    const float* gbf_b1    = (const float*)d_in[13];
    const float* gbf_W2    = (const float*)d_in[14];
    const float* gbf_b2    = (const float*)d_in[15];
    const float* dih_W1    = (const float*)d_in[16];
    const float* dih_b1    = (const float*)d_in[17];
    const float* dih_W2    = (const float*)d_in[18];
    const float* dih_b2    = (const float*)d_in[19];
    const float* ang_W1    = (const float*)d_in[20];
    const float* ang_b1    = (const float*)d_in[21];
    const float* ang_W2    = (const float*)d_in[22];
    const float* ang_b2    = (const float*)d_in[23];
    const int*   x         = (const int*)d_in[24];
    const int*   nte       = (const int*)d_in[25];

    float* out = (float*)d_out;
    float* out_attn  = out;                                  // [4,32,128,128]
    float* out_angle = out + (size_t)BB * HH * NN * NN;      // [4,128,256]
    float* out_dp    = out_angle + (size_t)BB * NN * DD;     // [4,128,128,3]

    float* ws = (float*)d_ws;
    float* keep    = ws;                       // 512
    float* no_pos  = ws + 512;                 // 4
    float* s_ws    = ws + 1024;                // 1536
    float* dist_ws = ws + 4096;                // 65536
    float* ld_ws   = ws + 4096 + 65536;        // 131072
    float* rd_ws   = ld_ws + (size_t)BB * NN * DD;   // 131072
    unsigned short* wp = (unsigned short*)(ws + 331776);
    unsigned short* Wp1    = wp;                 // 65536
    unsigned short* Wp2    = wp + 65536;         // 8192
    unsigned short* Wg1    = wp + 73728;         // 16384
    unsigned short* Wg2    = wp + 90112;         // 4096
    unsigned short* Wla_p  = wp + 94208;         // 65536
    unsigned short* Wra_p  = wp + 159744;        // 65536
    unsigned short* Wld_p  = wp + 225280;        // 65536
    unsigned short* Wrd_p  = wp + 290816;        // 65536
    unsigned short* WaW1_p = wp + 356352;        // 65536
    unsigned short* WaW2_p = wp + 421888;        // 65536  -> total ws ~2.30 MB

    k1_geom<<<dim3(BB * NN), dim3(NN), 0, stream>>>(pos, x, out_dp, dist_ws, s_ws, keep, no_pos);
    k_pack<<<dim3(238), dim3(256), 0, stream>>>(dih_W1, dih_W2, gbf_W1, gbf_W2,
                                                W_la, W_ra, W_ld, W_rd, ang_W1, ang_W2, wp);
    k2_mfma<<<dim3(16), dim3(256), 0, stream>>>(
        atom_emb, x, Wla_p, Wra_p, Wld_p, Wrd_p, WaW1_p, WaW2_p,
        ang_b1, ang_b2, s_ws, no_pos, ld_ws, rd_ws, out_angle);
    k3_mfma<<<dim3(BB * NN * 2), dim3(256), 0, stream>>>(
        Wp1, Wp2, Wg1, Wg2, dih_b1, dih_b2, gbf_b1, gbf_b2,
        gbf_means, gbf_stds, src_mul, tgt_mul, src_bias, tgt_bias, nte,
        ld_ws, rd_ws, s_ws, dist_ws, keep, no_pos, out_dp, out_attn);
}

// Round 8
// 157.671 us; speedup vs baseline: 2.5041x; 1.2432x over previous
//
#include <hip/hip_runtime.h>
#include <math.h>

#define BB 4
#define NN 128
#define DD 256
#define KK 128
#define HH 32
#define AA 128
#define EE 512

typedef float f32x4 __attribute__((ext_vector_type(4)));
typedef short short8 __attribute__((ext_vector_type(8)));
typedef unsigned short ushort4v __attribute__((ext_vector_type(4)));

// tanh-form GELU: x * sigmoid(2*0.7978845608*(x + 0.044715 x^3)); |err| <= ~3e-4
__device__ __forceinline__ float gelu_fast(float x) {
    float x2 = x * x;
    float t = x * fmaf(x2, 0.0713548162726f, 1.59576912161f);
    float e = __expf(-t);
    return x * __builtin_amdgcn_rcpf(1.0f + e);
}

__device__ __forceinline__ unsigned short f2bf(float f) {
    unsigned int u = __float_as_uint(f);
    u = u + 0x7fffu + ((u >> 16) & 1u);
    return (unsigned short)(u >> 16);
}

// byte-offset swizzles (XOR row into 16B-slot bit) for bank-conflict-free ds_read_b128
__device__ __forceinline__ int swz512(int row, int colByte) {   // 512B row stride
    return row * 512 + (colByte ^ ((row & 7) << 4));
}
__device__ __forceinline__ int swz256(int row, int colByte) {   // 256B row stride
    return row * 256 + (colByte ^ ((row & 7) << 4));
}

// ---------------- K1: masks + delta_pos + dist + s ----------------
__global__ void k1_geom(const float* __restrict__ pos, const int* __restrict__ x,
                        float* __restrict__ out_dp, float* __restrict__ dist_ws,
                        float* __restrict__ s_ws, float* __restrict__ keep,
                        float* __restrict__ no_pos) {
    int bi = blockIdx.x;            // b*N + i
    int b = bi >> 7;
    int i = bi & 127;
    int j = threadIdx.x;
    int bj = b * NN + j;

    int allz = 1;
    #pragma unroll
    for (int f = 0; f < 9; ++f) allz &= (x[bj * 9 + f] == 0);
    float kj = allz ? 0.0f : 1.0f;

    __shared__ int flag;
    if (j == 0) flag = 0;

    float pix = pos[bi * 3 + 0], piy = pos[bi * 3 + 1], piz = pos[bi * 3 + 2];
    float pjx = pos[bj * 3 + 0], pjy = pos[bj * 3 + 1], pjz = pos[bj * 3 + 2];
    float dx = pjx - pix, dy = pjy - piy, dz = pjz - piz;
    float dist = sqrtf(dx * dx + dy * dy + dz * dz);
    float inv = 1.0f / (dist + 1e-5f);
    dx *= inv; dy *= inv; dz *= inv;
    size_t e = (size_t)bi * NN + j;
    out_dp[e * 3 + 0] = dx;
    out_dp[e * 3 + 1] = dy;
    out_dp[e * 3 + 2] = dz;
    dist_ws[e] = dist;

    __shared__ float red[3][128];
    red[0][j] = kj * dx; red[1][j] = kj * dy; red[2][j] = kj * dz;
    __syncthreads();
    if (pjx != 0.0f || pjy != 0.0f || pjz != 0.0f) flag = 1;
    for (int off = 64; off > 0; off >>= 1) {
        if (j < off) {
            red[0][j] += red[0][j + off];
            red[1][j] += red[1][j + off];
            red[2][j] += red[2][j + off];
        }
        __syncthreads();
    }
    if (j == 0) {
        s_ws[bi * 3 + 0] = red[0][0];
        s_ws[bi * 3 + 1] = red[1][0];
        s_ws[bi * 3 + 2] = red[2][0];
    }
    if (i == 0) {
        keep[bj] = kj;
        if (j == 0) no_pos[b] = flag ? 1.0f : 0.0f;
    }
}

// ---------------- K_nf: embedding gather -> bf16 nf_ws [512][256] ----------------
__global__ __launch_bounds__(256) void k_nf(const float* __restrict__ atom_emb,
                                            const int* __restrict__ x,
                                            unsigned short* __restrict__ nf_ws) {
    int bn = blockIdx.x;
    int t = threadIdx.x;
    float acc = 0.0f;
    #pragma unroll
    for (int f = 0; f < 9; ++f) {
        int xi = x[bn * 9 + f];
        acc += atom_emb[((size_t)(f * (AA + 1) + xi)) * DD + t];
    }
    nf_ws[(size_t)bn * DD + t] = f2bf(acc);
}

// ---------------- K_pack: weights -> bf16 MFMA B-fragment layout (coalesced reads) ----------------
// Wp[((ks*ntiles + nt)*64 + l)*8 + e] = bf16( W[ks*32 + (l>>4)*8 + e][nt*16 + (l&15)] )
__global__ void k_pack(const float* __restrict__ dW1, const float* __restrict__ dW2,
                       const float* __restrict__ gW1, const float* __restrict__ gW2,
                       const float* __restrict__ wla, const float* __restrict__ wra,
                       const float* __restrict__ wld, const float* __restrict__ wrd,
                       const float* __restrict__ aW1, const float* __restrict__ aW2,
                       unsigned short* __restrict__ out) {
    int idx = blockIdx.x * 256 + threadIdx.x;   // 0..60927 (one thread = 8 consecutive cols of one row)
    const float* W; int Nc, base, k, c8;
    if (idx < 8192)       { W = dW1; Nc = 256; base = 0;     int li = idx;         k = li >> 5; c8 = li & 31; }
    else if (idx < 9216)  { W = dW2; Nc = 32;  base = 65536; int li = idx - 8192;  k = li >> 2; c8 = li & 3; }
    else if (idx < 11264) { W = gW1; Nc = 128; base = 73728; int li = idx - 9216;  k = li >> 4; c8 = li & 15; }
    else if (idx < 11776) { W = gW2; Nc = 32;  base = 90112; int li = idx - 11264; k = li >> 2; c8 = li & 3; }
    else if (idx < 60928) {
        int q  = (idx - 11776) >> 13;        // 0..5
        int li = (idx - 11776) & 8191;
        W = (q == 0) ? wla : (q == 1) ? wra : (q == 2) ? wld : (q == 3) ? wrd : (q == 4) ? aW1 : aW2;
        Nc = 256; base = 94208 + q * 65536; k = li >> 5; c8 = li & 31;
    }
    else return;
    int ntiles = Nc >> 4;
    int ks = k >> 5, hi = (k & 31) >> 3, ee = k & 7;
    const float* wp = &W[k * Nc + c8 * 8];
    float4 a = *reinterpret_cast<const float4*>(wp);
    float4 b4 = *reinterpret_cast<const float4*>(wp + 4);
    float vals[8] = {a.x, a.y, a.z, a.w, b4.x, b4.y, b4.z, b4.w};
    #pragma unroll
    for (int jj = 0; jj < 8; ++jj) {
        int c = c8 * 8 + jj;
        int nt = c >> 4, lo = c & 15;
        out[base + (((ks * ntiles + nt) * 64) + hi * 16 + lo) * 8 + ee] = f2bf(vals[jj]);
    }
}

// ---- stage a 32x256 bf16 row-major buffer into swizzled LDS (4 short8/thread) ----
__device__ __forceinline__ void stage32x256(const unsigned short* __restrict__ src, int bn0,
                                            unsigned short* sA, int t) {
    #pragma unroll
    for (int r = 0; r < 4; ++r) {
        int idx = r * 256 + t;
        int row = idx >> 5;
        int c8 = idx & 31;
        short8 v = *reinterpret_cast<const short8*>(&src[((size_t)(bn0 + row)) * DD + c8 * 8]);
        *reinterpret_cast<short8*>((char*)sA + swz512(row, c8 * 16)) = v;
    }
}

// ---- [32 x 256] @ B-chunk(16 cols, n-tile nt) -> acc[2] ----
__device__ __forceinline__ void gemm_nt(const unsigned short* __restrict__ Bp, int nt,
                                        const unsigned short* sA, int l, int lo, int hi,
                                        f32x4 acc[2]) {
    for (int ks = 0; ks < 8; ++ks) {
        short8 a0 = *reinterpret_cast<const short8*>((const char*)sA + swz512(lo, ks * 64 + hi * 16));
        short8 a1 = *reinterpret_cast<const short8*>((const char*)sA + swz512(16 + lo, ks * 64 + hi * 16));
        short8 bfr = *reinterpret_cast<const short8*>(&Bp[(((size_t)ks * 16 + nt) * 64 + l) * 8]);
        acc[0] = __builtin_amdgcn_mfma_f32_16x16x32_bf16(a0, bfr, acc[0], 0, 0, 0);
        acc[1] = __builtin_amdgcn_mfma_f32_16x16x32_bf16(a1, bfr, acc[1], 0, 0, 0);
    }
}

// ---------------- K2a: la/ra/ld/rd projections for one (node-tile, col-chunk) ----------------
// grid 64 = 16 node-tiles x 4 col-chunks; wave w owns 16 cols (nt = c*4+w)
__global__ __launch_bounds__(256, 4) void k2a(
    const unsigned short* __restrict__ nf_ws,
    const unsigned short* __restrict__ Wla_p, const unsigned short* __restrict__ Wra_p,
    const unsigned short* __restrict__ Wld_p, const unsigned short* __restrict__ Wrd_p,
    const float* __restrict__ s_ws,
    float* __restrict__ ld_ws, float* __restrict__ rd_ws,
    unsigned short* __restrict__ ap_ws) {
    int blk = blockIdx.x;
    int c = blk & 3, tile = blk >> 2;
    int bn0 = tile * 32;
    int t = threadIdx.x;
    int w = t >> 6, l = t & 63, lo = l & 15, hi = l >> 4;
    int nt = c * 4 + w;

    __shared__ __align__(16) unsigned short sA[32 * 256];
    __shared__ float ls2[32];
    if (t < 32) {
        float a0 = s_ws[(bn0 + t) * 3 + 0];
        float a1 = s_ws[(bn0 + t) * 3 + 1];
        float a2 = s_ws[(bn0 + t) * 3 + 2];
        ls2[t] = a0 * a0 + a1 * a1 + a2 * a2;
    }
    stage32x256(nf_ws, bn0, sA, t);
    __syncthreads();

    f32x4 a_la[2] = {}, a_ra[2] = {}, a_ld[2] = {}, a_rd[2] = {};
    gemm_nt(Wla_p, nt, sA, l, lo, hi, a_la);
    gemm_nt(Wra_p, nt, sA, l, lo, hi, a_ra);
    gemm_nt(Wld_p, nt, sA, l, lo, hi, a_ld);
    gemm_nt(Wrd_p, nt, sA, l, lo, hi, a_rd);

    int col = nt * 16 + lo;
    #pragma unroll
    for (int m = 0; m < 2; ++m) {
        #pragma unroll
        for (int r = 0; r < 4; ++r) {
            int row = m * 16 + hi * 4 + r;
            size_t off = (size_t)(bn0 + row) * DD + col;
            ld_ws[off] = a_ld[m][r];
            rd_ws[off] = a_rd[m][r];
            ap_ws[off] = f2bf(ls2[row] * a_la[m][r] * a_ra[m][r]);
        }
    }
}

// ---------------- K2b: angle MLP layer1 + gelu ----------------
__global__ __launch_bounds__(256, 4) void k2b(
    const unsigned short* __restrict__ ap_ws, const unsigned short* __restrict__ WaW1_p,
    const float* __restrict__ ang_b1, unsigned short* __restrict__ hid_ws) {
    int blk = blockIdx.x;
    int c = blk & 3, tile = blk >> 2;
    int bn0 = tile * 32;
    int t = threadIdx.x;
    int w = t >> 6, l = t & 63, lo = l & 15, hi = l >> 4;
    int nt = c * 4 + w;

    __shared__ __align__(16) unsigned short sA[32 * 256];
    stage32x256(ap_ws, bn0, sA, t);
    __syncthreads();

    f32x4 acc[2] = {};
    gemm_nt(WaW1_p, nt, sA, l, lo, hi, acc);

    int col = nt * 16 + lo;
    float b1v = ang_b1[col];
    #pragma unroll
    for (int m = 0; m < 2; ++m)
        #pragma unroll
        for (int r = 0; r < 4; ++r)
            hid_ws[(size_t)(bn0 + m * 16 + hi * 4 + r) * DD + col] = f2bf(gelu_fast(acc[m][r] + b1v));
}

// ---------------- K2c: angle MLP layer2 + bias + no_pos ----------------
__global__ __launch_bounds__(256, 4) void k2c(
    const unsigned short* __restrict__ hid_ws, const unsigned short* __restrict__ WaW2_p,
    const float* __restrict__ ang_b2, const float* __restrict__ no_pos,
    float* __restrict__ out_angle) {
    int blk = blockIdx.x;
    int c = blk & 3, tile = blk >> 2;
    int bn0 = tile * 32;
    int t = threadIdx.x;
    int w = t >> 6, l = t & 63, lo = l & 15, hi = l >> 4;
    int nt = c * 4 + w;

    __shared__ __align__(16) unsigned short sA[32 * 256];
    stage32x256(hid_ws, bn0, sA, t);
    __syncthreads();

    f32x4 acc[2] = {};
    gemm_nt(WaW2_p, nt, sA, l, lo, hi, acc);

    int col = nt * 16 + lo;
    float b2v = ang_b2[col];
    float lnp = no_pos[tile >> 2];
    #pragma unroll
    for (int m = 0; m < 2; ++m)
        #pragma unroll
        for (int r = 0; r < 4; ++r)
            out_angle[(size_t)(bn0 + m * 16 + hi * 4 + r) * DD + col] = (acc[m][r] + b2v) * lnp;
}

// ---------------- K3: MFMA edge kernel, 64 edges/block, 4 waves, staged A ----------------
__global__ __launch_bounds__(256, 2) void k3_mfma(
    const unsigned short* __restrict__ Wp1, const unsigned short* __restrict__ Wp2,
    const unsigned short* __restrict__ Wg1, const unsigned short* __restrict__ Wg2,
    const float* __restrict__ dih_b1, const float* __restrict__ dih_b2,
    const float* __restrict__ gbf_b1, const float* __restrict__ gbf_b2,
    const float* __restrict__ gbf_means, const float* __restrict__ gbf_stds,
    const float* __restrict__ src_mul, const float* __restrict__ tgt_mul,
    const float* __restrict__ src_bias, const float* __restrict__ tgt_bias,
    const int* __restrict__ nte,
    const float* __restrict__ ld_ws, const float* __restrict__ rd_ws,
    const float* __restrict__ s_ws, const float* __restrict__ dist_ws,
    const float* __restrict__ keep, const float* __restrict__ no_pos,
    const float* __restrict__ dp_in,
    float* __restrict__ out_attn) {
    int blk = blockIdx.x;           // b*256 + i*2 + jh
    int jh = blk & 1;
    int i  = (blk >> 1) & 127;
    int b  = blk >> 8;
    int j0 = jh * 64;
    int t = threadIdx.x;
    int w  = t >> 6;                // wave id 0..3
    int l  = t & 63;
    int lo = l & 15;
    int hi = l >> 4;

    __shared__ __align__(16) unsigned short sE[64 * 256];   // E bf16 swizzled; later aliased by sGH [64][128]
    __shared__ __align__(16) unsigned short sH[64 * 256];   // first 16KB holds sG before H is written
    __shared__ __align__(16) float rd_l[DD];
    __shared__ float sg[64], sxg[64], skeep[64];
    __shared__ __align__(16) float lmean[KK], linv[KK], lcoef[KK];

    int bi = b * NN + i;

    // ---- phase A: per-edge scalars + rd row + gaussian constants ----
    if (t < 64) {
        int j = j0 + t;
        size_t e = (size_t)bi * NN + j;
        float d0 = dp_in[e * 3 + 0], d1 = dp_in[e * 3 + 1], d2 = dp_in[e * 3 + 2];
        float si0 = s_ws[bi * 3 + 0], si1 = s_ws[bi * 3 + 1], si2 = s_ws[bi * 3 + 2];
        int bj = b * NN + j;
        float sj0 = s_ws[bj * 3 + 0], sj1 = s_ws[bj * 3 + 1], sj2 = s_ws[bj * 3 + 2];
        float u = sj0 * d0 + sj1 * d1 + sj2 * d2;
        float v = si0 * d0 + si1 * d1 + si2 * d2;
        float dp2 = d0 * d0 + d1 * d1 + d2 * d2;
        sg[t] = (si0 * sj0 + si1 * sj1 + si2 * sj2) - u * v * (2.0f - dp2);
        int et0 = nte[e * 2 + 0], et1 = nte[e * 2 + 1];
        sxg[t] = (src_mul[et0] + tgt_mul[et1]) * dist_ws[e] + src_bias[et0] + tgt_bias[et1];
        skeep[t] = keep[bj];
    } else if (t < 128) {
        int q = t - 64;
        reinterpret_cast<float4*>(rd_l)[q] =
            reinterpret_cast<const float4*>(&rd_ws[(size_t)bi * DD])[q];
    } else {
        int k = t - 128;
        float s = fabsf(gbf_stds[k]) + 0.01f;
        lmean[k] = gbf_means[k];
        linv[k] = 1.0f / s;
        lcoef[k] = 1.0f / (2.5066262f * s);
    }
    __syncthreads();

    // ---- phase B: build E (bf16, swizzled) and G (bf16, swizzled, inside sH) once ----
    {
        const float* ldbase = &ld_ws[((size_t)(b * NN + j0)) * DD];
        #pragma unroll
        for (int r = 0; r < 8; ++r) {
            int idx = r * 256 + t;
            int row = idx >> 5;          // 0..63
            int c8  = idx & 31;
            float g = sg[row];
            const float* lp = ldbase + row * DD + c8 * 8;
            float4 l0 = *reinterpret_cast<const float4*>(lp);
            float4 l1 = *reinterpret_cast<const float4*>(lp + 4);
            float4 r0 = *reinterpret_cast<const float4*>(&rd_l[c8 * 8]);
            float4 r1 = *reinterpret_cast<const float4*>(&rd_l[c8 * 8 + 4]);
            short8 vv;
            vv[0] = (short)f2bf(g * l0.x * r0.x);
            vv[1] = (short)f2bf(g * l0.y * r0.y);
            vv[2] = (short)f2bf(g * l0.z * r0.z);
            vv[3] = (short)f2bf(g * l0.w * r0.w);
            vv[4] = (short)f2bf(g * l1.x * r1.x);
            vv[5] = (short)f2bf(g * l1.y * r1.y);
            vv[6] = (short)f2bf(g * l1.z * r1.z);
            vv[7] = (short)f2bf(g * l1.w * r1.w);
            *reinterpret_cast<short8*>((char*)sE + swz512(row, c8 * 16)) = vv;
        }
        unsigned short* sG = sH;   // G lives in sH until H overwrites it (after sync)
        #pragma unroll
        for (int r = 0; r < 4; ++r) {
            int idx = r * 256 + t;
            int row = idx >> 4;          // 0..63
            int c8  = idx & 15;
            float xv = sxg[row];
            float4 m0 = *reinterpret_cast<const float4*>(&lmean[c8 * 8]);
            float4 m1 = *reinterpret_cast<const float4*>(&lmean[c8 * 8 + 4]);
            float4 i0 = *reinterpret_cast<const float4*>(&linv[c8 * 8]);
            float4 i1 = *reinterpret_cast<const float4*>(&linv[c8 * 8 + 4]);
            float4 c0 = *reinterpret_cast<const float4*>(&lcoef[c8 * 8]);
            float4 c1 = *reinterpret_cast<const float4*>(&lcoef[c8 * 8 + 4]);
            float z;
            short8 vv;
            z = (xv - m0.x) * i0.x; vv[0] = (short)f2bf(c0.x * __expf(-0.5f * z * z));
            z = (xv - m0.y) * i0.y; vv[1] = (short)f2bf(c0.y * __expf(-0.5f * z * z));
            z = (xv - m0.z) * i0.z; vv[2] = (short)f2bf(c0.z * __expf(-0.5f * z * z));
            z = (xv - m0.w) * i0.w; vv[3] = (short)f2bf(c0.w * __expf(-0.5f * z * z));
            z = (xv - m1.x) * i1.x; vv[4] = (short)f2bf(c1.x * __expf(-0.5f * z * z));
            z = (xv - m1.y) * i1.y; vv[5] = (short)f2bf(c1.y * __expf(-0.5f * z * z));
            z = (xv - m1.z) * i1.z; vv[6] = (short)f2bf(c1.z * __expf(-0.5f * z * z));
            z = (xv - m1.w) * i1.w; vv[7] = (short)f2bf(c1.w * __expf(-0.5f * z * z));
            *reinterpret_cast<short8*>((char*)sG + swz256(row, c8 * 16)) = vv;
        }
    }
    __syncthreads();

    // ---- phase C: GEMM1-gbf (reads sG) and GEMM1-dih (reads sE); no LDS writes ----
    f32x4 accg[4][2] = {};
    {
        const unsigned short* sG = sH;
        for (int ks = 0; ks < 4; ++ks) {
            short8 a[4];
            #pragma unroll
            for (int m = 0; m < 4; ++m)
                a[m] = *reinterpret_cast<const short8*>((const char*)sG + swz256(m * 16 + lo, ks * 64 + hi * 16));
            #pragma unroll
            for (int n = 0; n < 2; ++n) {
                short8 bfr = *reinterpret_cast<const short8*>(&Wg1[(((size_t)ks * 8 + (w * 2 + n)) * 64 + l) * 8]);
                #pragma unroll
                for (int m = 0; m < 4; ++m)
                    accg[m][n] = __builtin_amdgcn_mfma_f32_16x16x32_bf16(a[m], bfr, accg[m][n], 0, 0, 0);
            }
        }
    }
    f32x4 acc[4][4] = {};
    for (int ks = 0; ks < 8; ++ks) {
        short8 a[4];
        #pragma unroll
        for (int m = 0; m < 4; ++m)
            a[m] = *reinterpret_cast<const short8*>((const char*)sE + swz512(m * 16 + lo, ks * 64 + hi * 16));
        #pragma unroll
        for (int n = 0; n < 4; ++n) {
            short8 bfr = *reinterpret_cast<const short8*>(&Wp1[(((size_t)ks * 16 + (w * 4 + n)) * 64 + l) * 8]);
            #pragma unroll
            for (int m = 0; m < 4; ++m)
                acc[m][n] = __builtin_amdgcn_mfma_f32_16x16x32_bf16(a[m], bfr, acc[m][n], 0, 0, 0);
        }
    }
    __syncthreads();

    // ---- phase D: gelu + write H (sH) and HG (alias over sE) ----
    {
        #pragma unroll
        for (int n = 0; n < 4; ++n) {
            int col = w * 64 + n * 16 + lo;
            float b1v = dih_b1[col];
            #pragma unroll
            for (int m = 0; m < 4; ++m) {
                int row0 = m * 16 + hi * 4;
                #pragma unroll
                for (int r = 0; r < 4; ++r) {
                    *reinterpret_cast<unsigned short*>((char*)sH + swz512(row0 + r, col * 2)) =
                        f2bf(gelu_fast(acc[m][n][r] + b1v));
                }
            }
        }
        unsigned short* sGH = sE;   // sE dead
        #pragma unroll
        for (int n = 0; n < 2; ++n) {
            int col = w * 32 + n * 16 + lo;
            float b1v = gbf_b1[col];
            #pragma unroll
            for (int m = 0; m < 4; ++m) {
                int row0 = m * 16 + hi * 4;
                #pragma unroll
                for (int r = 0; r < 4; ++r) {
                    *reinterpret_cast<unsigned short*>((char*)sGH + swz256(row0 + r, col * 2)) =
                        f2bf(gelu_fast(accg[m][n][r] + b1v));
                }
            }
        }
    }
    __syncthreads();

    // ---- phase E: GEMM2-dih + GEMM2-gbf + epilogue ----
    f32x4 acc2d[2] = {};
    for (int ks = 0; ks < 8; ++ks) {
        short8 a = *reinterpret_cast<const short8*>((const char*)sH + swz512(w * 16 + lo, ks * 64 + hi * 16));
        #pragma unroll
        for (int n = 0; n < 2; ++n) {
            short8 bfr = *reinterpret_cast<const short8*>(&Wp2[(((size_t)ks * 2 + n) * 64 + l) * 8]);
            acc2d[n] = __builtin_amdgcn_mfma_f32_16x16x32_bf16(a, bfr, acc2d[n], 0, 0, 0);
        }
    }
    f32x4 acc2g[2] = {};
    {
        const unsigned short* sGH = sE;
        for (int ks = 0; ks < 4; ++ks) {
            short8 a = *reinterpret_cast<const short8*>((const char*)sGH + swz256(w * 16 + lo, ks * 64 + hi * 16));
            #pragma unroll
            for (int n = 0; n < 2; ++n) {
                short8 bfr = *reinterpret_cast<const short8*>(&Wg2[(((size_t)ks * 2 + n) * 64 + l) * 8]);
                acc2g[n] = __builtin_amdgcn_mfma_f32_16x16x32_bf16(a, bfr, acc2g[n], 0, 0, 0);
            }
        }
    }

    float npos = no_pos[b];
    int e0 = w * 16 + hi * 4;
    #pragma unroll
    for (int n = 0; n < 2; ++n) {
        int h = n * 16 + lo;
        float bsum = dih_b2[h] + gbf_b2[h];
        float4 v;
        float vr;
        vr = (acc2d[n][0] + acc2g[n][0] + bsum) * npos; v.x = (skeep[e0 + 0] == 0.0f) ? -INFINITY : vr;
        vr = (acc2d[n][1] + acc2g[n][1] + bsum) * npos; v.y = (skeep[e0 + 1] == 0.0f) ? -INFINITY : vr;
        vr = (acc2d[n][2] + acc2g[n][2] + bsum) * npos; v.z = (skeep[e0 + 2] == 0.0f) ? -INFINITY : vr;
        vr = (acc2d[n][3] + acc2g[n][3] + bsum) * npos; v.w = (skeep[e0 + 3] == 0.0f) ? -INFINITY : vr;
        *reinterpret_cast<float4*>(&out_attn[(((size_t)b * HH + h) * NN + i) * NN + j0 + e0]) = v;
    }
}

extern "C" void kernel_launch(void* const* d_in, const int* in_sizes, int n_in,
                              void* d_out, int out_size, void* d_ws, size_t ws_size,
                              hipStream_t stream) {
    const float* pos       = (const float*)d_in[0];
    const float* atom_emb  = (const float*)d_in[1];
    const float* W_la      = (const float*)d_in[2];
    const float* W_ra      = (const float*)d_in[3];
    const float* W_ld      = (const float*)d_in[4];
    const float* W_rd      = (const float*)d_in[5];
    const float* gbf_means = (const float*)d_in[6];
    const float* gbf_stds  = (const float*)d_in[7];
    const float* src_mul   = (const float*)d_in[8];
    const float* tgt_mul   = (const float*)d_in[9];
    const float* src_bias  = (const float*)d_in[10];
    const float* tgt_bias  = (const float*)d_in[11];
    const float* gbf_W1    = (const float*)d_in[12];
    const float* gbf_b1    = (const float*)d_in[13];
    const float* gbf_W2    = (const float*)d_in[14];
    const float* gbf_b2    = (const float*)d_in[15];
    const float* dih_W1    = (const float*)d_in[16];
    const float* dih_b1    = (const float*)d_in[17];
    const float* dih_W2    = (const float*)d_in[18];
    const float* dih_b2    = (const float*)d_in[19];
    const float* ang_W1    = (const float*)d_in[20];
    const float* ang_b1    = (const float*)d_in[21];
    const float* ang_W2    = (const float*)d_in[22];
    const float* ang_b2    = (const float*)d_in[23];
    const int*   x         = (const int*)d_in[24];
    const int*   nte       = (const int*)d_in[25];

    float* out = (float*)d_out;
    float* out_attn  = out;                                  // [4,32,128,128]
    float* out_angle = out + (size_t)BB * HH * NN * NN;      // [4,128,256]
    float* out_dp    = out_angle + (size_t)BB * NN * DD;     // [4,128,128,3]

    float* ws = (float*)d_ws;
    float* keep    = ws;                       // 512
    float* no_pos  = ws + 512;                 // 4
    float* s_ws    = ws + 1024;                // 1536
    float* dist_ws = ws + 4096;                // 65536
    float* ld_ws   = ws + 4096 + 65536;        // 131072
    float* rd_ws   = ld_ws + (size_t)BB * NN * DD;   // 131072
    unsigned short* wp = (unsigned short*)(ws + 331776);
    unsigned short* Wp1    = wp;                 // 65536
    unsigned short* Wp2    = wp + 65536;         // 8192
    unsigned short* Wg1    = wp + 73728;         // 16384
    unsigned short* Wg2    = wp + 90112;         // 4096
    unsigned short* Wla_p  = wp + 94208;         // 65536
    unsigned short* Wra_p  = wp + 159744;        // 65536
    unsigned short* Wld_p  = wp + 225280;        // 65536
    unsigned short* Wrd_p  = wp + 290816;        // 65536
    unsigned short* WaW1_p = wp + 356352;        // 65536
    unsigned short* WaW2_p = wp + 421888;        // 65536  -> ends at f32 offset 575488
    unsigned short* nf_ws  = (unsigned short*)(ws + 575488);   // 131072 ushorts
    unsigned short* ap_ws  = (unsigned short*)(ws + 641024);   // 131072 ushorts
    unsigned short* hid_ws = (unsigned short*)(ws + 706560);   // 131072 ushorts -> ~3.09 MB total

    k1_geom<<<dim3(BB * NN), dim3(NN), 0, stream>>>(pos, x, out_dp, dist_ws, s_ws, keep, no_pos);
    k_nf<<<dim3(BB * NN), dim3(256), 0, stream>>>(atom_emb, x, nf_ws);
    k_pack<<<dim3(238), dim3(256), 0, stream>>>(dih_W1, dih_W2, gbf_W1, gbf_W2,
                                                W_la, W_ra, W_ld, W_rd, ang_W1, ang_W2, wp);
    k2a<<<dim3(64), dim3(256), 0, stream>>>(nf_ws, Wla_p, Wra_p, Wld_p, Wrd_p,
                                            s_ws, ld_ws, rd_ws, ap_ws);
    k2b<<<dim3(64), dim3(256), 0, stream>>>(ap_ws, WaW1_p, ang_b1, hid_ws);
    k2c<<<dim3(64), dim3(256), 0, stream>>>(hid_ws, WaW2_p, ang_b2, no_pos, out_angle);
    k3_mfma<<<dim3(BB * NN * 2), dim3(256), 0, stream>>>(
        Wp1, Wp2, Wg1, Wg2, dih_b1, dih_b2, gbf_b1, gbf_b2,
        gbf_means, gbf_stds, src_mul, tgt_mul, src_bias, tgt_bias, nte,
        ld_ws, rd_ws, s_ws, dist_ws, keep, no_pos, out_dp, out_attn);
}

// Round 10
// 149.546 us; speedup vs baseline: 2.6402x; 1.0543x over previous
//
#include <hip/hip_runtime.h>
#include <math.h>

#define BB 4
#define NN 128
#define DD 256
#define KK 128
#define HH 32
#define AA 128
#define EE 512

typedef float f32x4 __attribute__((ext_vector_type(4)));
typedef short short8 __attribute__((ext_vector_type(8)));

// tanh-form GELU: x * sigmoid(2*0.7978845608*(x + 0.044715 x^3)); |err| <= ~3e-4
__device__ __forceinline__ float gelu_fast(float x) {
    float x2 = x * x;
    float t = x * fmaf(x2, 0.0713548162726f, 1.59576912161f);
    float e = __expf(-t);
    return x * __builtin_amdgcn_rcpf(1.0f + e);
}

__device__ __forceinline__ unsigned short f2bf(float f) {
    unsigned int u = __float_as_uint(f);
    u = u + 0x7fffu + ((u >> 16) & 1u);
    return (unsigned short)(u >> 16);
}

// byte-offset swizzles (XOR row into 16B-slot bit) for bank-conflict-free ds_read_b128
__device__ __forceinline__ int swz512(int row, int colByte) {   // 512B row stride
    return row * 512 + (colByte ^ ((row & 7) << 4));
}
__device__ __forceinline__ int swz256(int row, int colByte) {   // 256B row stride
    return row * 256 + (colByte ^ ((row & 7) << 4));
}

// ================ K_setup: fused k1_geom (blk<512) + k_nf (blk<1024) + k_pack ================
__global__ __launch_bounds__(256) void k_setup(
    const float* __restrict__ pos, const int* __restrict__ x,
    const float* __restrict__ atom_emb,
    const float* __restrict__ dW1, const float* __restrict__ dW2,
    const float* __restrict__ gW1, const float* __restrict__ gW2,
    const float* __restrict__ wla, const float* __restrict__ wra,
    const float* __restrict__ wld, const float* __restrict__ wrd,
    const float* __restrict__ aW1, const float* __restrict__ aW2,
    float* __restrict__ out_dp, float* __restrict__ dist_ws,
    float* __restrict__ s_ws, float* __restrict__ keep, float* __restrict__ no_pos,
    unsigned short* __restrict__ nf_ws, unsigned short* __restrict__ wpack) {
    int blk = blockIdx.x;
    int t = threadIdx.x;

    if (blk < 512) {
        // ---- k1 role: geometry for row i = blk (threads 0..127 active) ----
        int bi = blk;
        int b = bi >> 7;
        int i = bi & 127;
        __shared__ float red[3][128];
        __shared__ int flag;
        if (t == 0) flag = 0;
        float kj = 0.0f, dx = 0.0f, dy = 0.0f, dz = 0.0f;
        float pjx = 0.0f, pjy = 0.0f, pjz = 0.0f;
        int bj = b * NN + (t & 127);
        if (t < 128) {
            int j = t;
            int allz = 1;
            #pragma unroll
            for (int f = 0; f < 9; ++f) allz &= (x[bj * 9 + f] == 0);
            kj = allz ? 0.0f : 1.0f;
            float pix = pos[bi * 3 + 0], piy = pos[bi * 3 + 1], piz = pos[bi * 3 + 2];
            pjx = pos[bj * 3 + 0]; pjy = pos[bj * 3 + 1]; pjz = pos[bj * 3 + 2];
            dx = pjx - pix; dy = pjy - piy; dz = pjz - piz;
            float dist = sqrtf(dx * dx + dy * dy + dz * dz);
            float inv = 1.0f / (dist + 1e-5f);
            dx *= inv; dy *= inv; dz *= inv;
            size_t e = (size_t)bi * NN + j;
            out_dp[e * 3 + 0] = dx;
            out_dp[e * 3 + 1] = dy;
            out_dp[e * 3 + 2] = dz;
            dist_ws[e] = dist;
            red[0][j] = kj * dx; red[1][j] = kj * dy; red[2][j] = kj * dz;
        }
        __syncthreads();
        if (t < 128) {
            if (pjx != 0.0f || pjy != 0.0f || pjz != 0.0f) flag = 1;
        }
        for (int off = 64; off > 0; off >>= 1) {
            if (t < off) {
                red[0][t] += red[0][t + off];
                red[1][t] += red[1][t + off];
                red[2][t] += red[2][t + off];
            }
            __syncthreads();
        }
        if (t == 0) {
            s_ws[bi * 3 + 0] = red[0][0];
            s_ws[bi * 3 + 1] = red[1][0];
            s_ws[bi * 3 + 2] = red[2][0];
        }
        if (i == 0 && t < 128) {
            keep[bj] = kj;
            if (t == 0) no_pos[b] = flag ? 1.0f : 0.0f;
        }
        return;
    }

    if (blk < 1024) {
        // ---- k_nf role: embedding gather for node bn = blk-512 ----
        int bn = blk - 512;
        float acc = 0.0f;
        #pragma unroll
        for (int f = 0; f < 9; ++f) {
            int xi = x[bn * 9 + f];
            acc += atom_emb[((size_t)(f * (AA + 1) + xi)) * DD + t];
        }
        nf_ws[(size_t)bn * DD + t] = f2bf(acc);
        return;
    }

    // ---- k_pack role: weights -> bf16 MFMA B-fragment layout ----
    // Wp[((ks*ntiles + nt)*64 + l)*8 + e] = bf16( W[ks*32 + (l>>4)*8 + e][nt*16 + (l&15)] )
    {
        int idx = (blk - 1024) * 256 + t;   // 0..60927
        const float* W; int Nc, base, k, c8;
        if (idx < 8192)       { W = dW1; Nc = 256; base = 0;     int li = idx;         k = li >> 5; c8 = li & 31; }
        else if (idx < 9216)  { W = dW2; Nc = 32;  base = 65536; int li = idx - 8192;  k = li >> 2; c8 = li & 3; }
        else if (idx < 11264) { W = gW1; Nc = 128; base = 73728; int li = idx - 9216;  k = li >> 4; c8 = li & 15; }
        else if (idx < 11776) { W = gW2; Nc = 32;  base = 90112; int li = idx - 11264; k = li >> 2; c8 = li & 3; }
        else if (idx < 60928) {
            int q  = (idx - 11776) >> 13;        // 0..5
            int li = (idx - 11776) & 8191;
            W = (q == 0) ? wla : (q == 1) ? wra : (q == 2) ? wld : (q == 3) ? wrd : (q == 4) ? aW1 : aW2;
            Nc = 256; base = 94208 + q * 65536; k = li >> 5; c8 = li & 31;
        }
        else return;
        int ntiles = Nc >> 4;
        int ks = k >> 5, hi = (k & 31) >> 3, ee = k & 7;
        const float* wp = &W[k * Nc + c8 * 8];
        float4 a = *reinterpret_cast<const float4*>(wp);
        float4 b4 = *reinterpret_cast<const float4*>(wp + 4);
        float vals[8] = {a.x, a.y, a.z, a.w, b4.x, b4.y, b4.z, b4.w};
        #pragma unroll
        for (int jj = 0; jj < 8; ++jj) {
            int c = c8 * 8 + jj;
            int nt = c >> 4, lo = c & 15;
            wpack[base + (((ks * ntiles + nt) * 64) + hi * 16 + lo) * 8 + ee] = f2bf(vals[jj]);
        }
    }
}

// ---- stage a 32x256 bf16 row-major buffer into swizzled LDS (4 short8/thread) ----
__device__ __forceinline__ void stage32x256(const unsigned short* __restrict__ src, int bn0,
                                            unsigned short* sA, int t) {
    #pragma unroll
    for (int r = 0; r < 4; ++r) {
        int idx = r * 256 + t;
        int row = idx >> 5;
        int c8 = idx & 31;
        short8 v = *reinterpret_cast<const short8*>(&src[((size_t)(bn0 + row)) * DD + c8 * 8]);
        *reinterpret_cast<short8*>((char*)sA + swz512(row, c8 * 16)) = v;
    }
}

// ---- [32 x 256] @ B-chunk(16 cols, n-tile nt) -> acc[2] ----
__device__ __forceinline__ void gemm_nt(const unsigned short* __restrict__ Bp, int nt,
                                        const unsigned short* sA, int l, int lo, int hi,
                                        f32x4 acc[2]) {
    for (int ks = 0; ks < 8; ++ks) {
        short8 a0 = *reinterpret_cast<const short8*>((const char*)sA + swz512(lo, ks * 64 + hi * 16));
        short8 a1 = *reinterpret_cast<const short8*>((const char*)sA + swz512(16 + lo, ks * 64 + hi * 16));
        short8 bfr = *reinterpret_cast<const short8*>(&Bp[(((size_t)ks * 16 + nt) * 64 + l) * 8]);
        acc[0] = __builtin_amdgcn_mfma_f32_16x16x32_bf16(a0, bfr, acc[0], 0, 0, 0);
        acc[1] = __builtin_amdgcn_mfma_f32_16x16x32_bf16(a1, bfr, acc[1], 0, 0, 0);
    }
}

// ---- [32 x 256] @ [256 x 256] chunk GEMM, wave w owns cols w*64..w*64+63 ----
__device__ __forceinline__ void gemm_chunk32(const unsigned short* __restrict__ Bp,
                                             const unsigned short* sAp,
                                             int w, int l, int lo, int hi,
                                             f32x4 acc[2][4]) {
    for (int ks = 0; ks < 8; ++ks) {
        short8 a[2];
        #pragma unroll
        for (int m = 0; m < 2; ++m)
            a[m] = *reinterpret_cast<const short8*>((const char*)sAp + swz512(m * 16 + lo, ks * 64 + hi * 16));
        #pragma unroll
        for (int n = 0; n < 4; ++n) {
            short8 bfr = *reinterpret_cast<const short8*>(&Bp[(((size_t)ks * 16 + (w * 4 + n)) * 64 + l) * 8]);
            #pragma unroll
            for (int m = 0; m < 2; ++m)
                acc[m][n] = __builtin_amdgcn_mfma_f32_16x16x32_bf16(a[m], bfr, acc[m][n], 0, 0, 0);
        }
    }
}

// ================ K2a: la/ra/ld/rd projections for one (node-tile, col-chunk) ================
// grid 64 = 16 node-tiles x 4 col-chunks; wave w owns 16 cols (nt = c*4+w)
__global__ __launch_bounds__(256, 4) void k2a(
    const unsigned short* __restrict__ nf_ws,
    const unsigned short* __restrict__ Wla_p, const unsigned short* __restrict__ Wra_p,
    const unsigned short* __restrict__ Wld_p, const unsigned short* __restrict__ Wrd_p,
    const float* __restrict__ s_ws,
    float* __restrict__ ld_ws, float* __restrict__ rd_ws,
    unsigned short* __restrict__ ap_ws) {
    int blk = blockIdx.x;
    int c = blk & 3, tile = blk >> 2;
    int bn0 = tile * 32;
    int t = threadIdx.x;
    int w = t >> 6, l = t & 63, lo = l & 15, hi = l >> 4;
    int nt = c * 4 + w;

    __shared__ __align__(16) unsigned short sA[32 * 256];
    __shared__ float ls2[32];
    if (t < 32) {
        float a0 = s_ws[(bn0 + t) * 3 + 0];
        float a1 = s_ws[(bn0 + t) * 3 + 1];
        float a2 = s_ws[(bn0 + t) * 3 + 2];
        ls2[t] = a0 * a0 + a1 * a1 + a2 * a2;
    }
    stage32x256(nf_ws, bn0, sA, t);
    __syncthreads();

    f32x4 a_la[2] = {}, a_ra[2] = {}, a_ld[2] = {}, a_rd[2] = {};
    gemm_nt(Wla_p, nt, sA, l, lo, hi, a_la);
    gemm_nt(Wra_p, nt, sA, l, lo, hi, a_ra);
    gemm_nt(Wld_p, nt, sA, l, lo, hi, a_ld);
    gemm_nt(Wrd_p, nt, sA, l, lo, hi, a_rd);

    int col = nt * 16 + lo;
    #pragma unroll
    for (int m = 0; m < 2; ++m) {
        #pragma unroll
        for (int r = 0; r < 4; ++r) {
            int row = m * 16 + hi * 4 + r;
            size_t off = (size_t)(bn0 + row) * DD + col;
            ld_ws[off] = a_ld[m][r];
            rd_ws[off] = a_rd[m][r];
            ap_ws[off] = f2bf(ls2[row] * a_la[m][r] * a_ra[m][r]);
        }
    }
}

// ================ K_mega: blocks 0..15 = angle MLP (k2bc); blocks 16+ = edge kernel (k3) ================
__global__ __launch_bounds__(256, 2) void k_mega(
    const unsigned short* __restrict__ Wp1, const unsigned short* __restrict__ Wp2,
    const unsigned short* __restrict__ Wg1, const unsigned short* __restrict__ Wg2,
    const unsigned short* __restrict__ WaW1_p, const unsigned short* __restrict__ WaW2_p,
    const float* __restrict__ dih_b1, const float* __restrict__ dih_b2,
    const float* __restrict__ gbf_b1, const float* __restrict__ gbf_b2,
    const float* __restrict__ ang_b1, const float* __restrict__ ang_b2,
    const float* __restrict__ gbf_means, const float* __restrict__ gbf_stds,
    const float* __restrict__ src_mul, const float* __restrict__ tgt_mul,
    const float* __restrict__ src_bias, const float* __restrict__ tgt_bias,
    const int* __restrict__ nte,
    const unsigned short* __restrict__ ap_ws,
    const float* __restrict__ ld_ws, const float* __restrict__ rd_ws,
    const float* __restrict__ s_ws, const float* __restrict__ dist_ws,
    const float* __restrict__ keep, const float* __restrict__ no_pos,
    const float* __restrict__ dp_in,
    float* __restrict__ out_angle, float* __restrict__ out_attn) {
    int t = threadIdx.x;
    int w  = t >> 6;                // wave id 0..3
    int l  = t & 63;
    int lo = l & 15;
    int hi = l >> 4;

    __shared__ __align__(16) unsigned short sE[64 * 256];   // k3: E; k2bc: sA (first 16KB)
    __shared__ __align__(16) unsigned short sH[64 * 256];   // k3: G then H; k2bc: sB (first 16KB)
    __shared__ __align__(16) float rd_l[DD];
    __shared__ float sg[64], sxg[64], skeep[64];
    __shared__ __align__(16) float lmean[KK], linv[KK], lcoef[KK];

    if (blockIdx.x < 16) {
        // ======== k2bc role: full-width angle MLP for 32-node tile ========
        int tile = blockIdx.x;
        int bn0 = tile * 32;
        stage32x256(ap_ws, bn0, sE, t);
        __syncthreads();
        {
            f32x4 acc[2][4] = {};
            gemm_chunk32(WaW1_p, sE, w, l, lo, hi, acc);
            #pragma unroll
            for (int n = 0; n < 4; ++n) {
                int col = w * 64 + n * 16 + lo;
                float b1v = ang_b1[col];
                #pragma unroll
                for (int m = 0; m < 2; ++m)
                    #pragma unroll
                    for (int r = 0; r < 4; ++r) {
                        int row = m * 16 + hi * 4 + r;
                        *reinterpret_cast<unsigned short*>((char*)sH + swz512(row, col * 2)) =
                            f2bf(gelu_fast(acc[m][n][r] + b1v));
                    }
            }
        }
        __syncthreads();
        {
            f32x4 acc[2][4] = {};
            gemm_chunk32(WaW2_p, sH, w, l, lo, hi, acc);
            float lnp = no_pos[tile >> 2];
            #pragma unroll
            for (int n = 0; n < 4; ++n) {
                int col = w * 64 + n * 16 + lo;
                float b2v = ang_b2[col];
                #pragma unroll
                for (int m = 0; m < 2; ++m)
                    #pragma unroll
                    for (int r = 0; r < 4; ++r) {
                        int row = m * 16 + hi * 4 + r;
                        out_angle[(size_t)(bn0 + row) * DD + col] = (acc[m][n][r] + b2v) * lnp;
                    }
            }
        }
        return;
    }

    // ======== k3 role: edge kernel, 64 edges/block ========
    int blk = blockIdx.x - 16;      // b*256 + i*2 + jh
    int jh = blk & 1;
    int i  = (blk >> 1) & 127;
    int b  = blk >> 8;
    int j0 = jh * 64;

    int bi = b * NN + i;

    // ---- phase A: per-edge scalars + rd row + gaussian constants ----
    if (t < 64) {
        int j = j0 + t;
        size_t e = (size_t)bi * NN + j;
        float d0 = dp_in[e * 3 + 0], d1 = dp_in[e * 3 + 1], d2 = dp_in[e * 3 + 2];
        float si0 = s_ws[bi * 3 + 0], si1 = s_ws[bi * 3 + 1], si2 = s_ws[bi * 3 + 2];
        int bj = b * NN + j;
        float sj0 = s_ws[bj * 3 + 0], sj1 = s_ws[bj * 3 + 1], sj2 = s_ws[bj * 3 + 2];
        float u = sj0 * d0 + sj1 * d1 + sj2 * d2;
        float v = si0 * d0 + si1 * d1 + si2 * d2;
        float dp2 = d0 * d0 + d1 * d1 + d2 * d2;
        sg[t] = (si0 * sj0 + si1 * sj1 + si2 * sj2) - u * v * (2.0f - dp2);
        int et0 = nte[e * 2 + 0], et1 = nte[e * 2 + 1];
        sxg[t] = (src_mul[et0] + tgt_mul[et1]) * dist_ws[e] + src_bias[et0] + tgt_bias[et1];
        skeep[t] = keep[bj];
    } else if (t < 128) {
        int q = t - 64;
        reinterpret_cast<float4*>(rd_l)[q] =
            reinterpret_cast<const float4*>(&rd_ws[(size_t)bi * DD])[q];
    } else {
        int k = t - 128;
        float s = fabsf(gbf_stds[k]) + 0.01f;
        lmean[k] = gbf_means[k];
        linv[k] = 1.0f / s;
        lcoef[k] = 1.0f / (2.5066262f * s);
    }
    __syncthreads();

    // ---- phase B: build E (bf16, swizzled) and G (bf16, swizzled, inside sH) once ----
    {
        const float* ldbase = &ld_ws[((size_t)(b * NN + j0)) * DD];
        #pragma unroll
        for (int r = 0; r < 8; ++r) {
            int idx = r * 256 + t;
            int row = idx >> 5;          // 0..63
            int c8  = idx & 31;
            float g = sg[row];
            const float* lp = ldbase + row * DD + c8 * 8;
            float4 l0 = *reinterpret_cast<const float4*>(lp);
            float4 l1 = *reinterpret_cast<const float4*>(lp + 4);
            float4 r0 = *reinterpret_cast<const float4*>(&rd_l[c8 * 8]);
            float4 r1 = *reinterpret_cast<const float4*>(&rd_l[c8 * 8 + 4]);
            short8 vv;
            vv[0] = (short)f2bf(g * l0.x * r0.x);
            vv[1] = (short)f2bf(g * l0.y * r0.y);
            vv[2] = (short)f2bf(g * l0.z * r0.z);
            vv[3] = (short)f2bf(g * l0.w * r0.w);
            vv[4] = (short)f2bf(g * l1.x * r1.x);
            vv[5] = (short)f2bf(g * l1.y * r1.y);
            vv[6] = (short)f2bf(g * l1.z * r1.z);
            vv[7] = (short)f2bf(g * l1.w * r1.w);
            *reinterpret_cast<short8*>((char*)sE + swz512(row, c8 * 16)) = vv;
        }
        unsigned short* sG = sH;   // G lives in sH until H overwrites it (after sync)
        #pragma unroll
        for (int r = 0; r < 4; ++r) {
            int idx = r * 256 + t;
            int row = idx >> 4;          // 0..63
            int c8  = idx & 15;
            float xv = sxg[row];
            float4 m0 = *reinterpret_cast<const float4*>(&lmean[c8 * 8]);
            float4 m1 = *reinterpret_cast<const float4*>(&lmean[c8 * 8 + 4]);
            float4 i0 = *reinterpret_cast<const float4*>(&linv[c8 * 8]);
            float4 i1 = *reinterpret_cast<const float4*>(&linv[c8 * 8 + 4]);
            float4 c0 = *reinterpret_cast<const float4*>(&lcoef[c8 * 8]);
            float4 c1 = *reinterpret_cast<const float4*>(&lcoef[c8 * 8 + 4]);
            float z;
            short8 vv;
            z = (xv - m0.x) * i0.x; vv[0] = (short)f2bf(c0.x * __expf(-0.5f * z * z));
            z = (xv - m0.y) * i0.y; vv[1] = (short)f2bf(c0.y * __expf(-0.5f * z * z));
            z = (xv - m0.z) * i0.z; vv[2] = (short)f2bf(c0.z * __expf(-0.5f * z * z));
            z = (xv - m0.w) * i0.w; vv[3] = (short)f2bf(c0.w * __expf(-0.5f * z * z));
            z = (xv - m1.x) * i1.x; vv[4] = (short)f2bf(c1.x * __expf(-0.5f * z * z));
            z = (xv - m1.y) * i1.y; vv[5] = (short)f2bf(c1.y * __expf(-0.5f * z * z));
            z = (xv - m1.z) * i1.z; vv[6] = (short)f2bf(c1.z * __expf(-0.5f * z * z));
            z = (xv - m1.w) * i1.w; vv[7] = (short)f2bf(c1.w * __expf(-0.5f * z * z));
            *reinterpret_cast<short8*>((char*)sG + swz256(row, c8 * 16)) = vv;
        }
    }
    __syncthreads();

    // ---- phase C: GEMM1-gbf (reads sG) and GEMM1-dih (reads sE); no LDS writes ----
    f32x4 accg[4][2] = {};
    {
        const unsigned short* sG = sH;
        for (int ks = 0; ks < 4; ++ks) {
            short8 a[4];
            #pragma unroll
            for (int m = 0; m < 4; ++m)
                a[m] = *reinterpret_cast<const short8*>((const char*)sG + swz256(m * 16 + lo, ks * 64 + hi * 16));
            #pragma unroll
            for (int n = 0; n < 2; ++n) {
                short8 bfr = *reinterpret_cast<const short8*>(&Wg1[(((size_t)ks * 8 + (w * 2 + n)) * 64 + l) * 8]);
                #pragma unroll
                for (int m = 0; m < 4; ++m)
                    accg[m][n] = __builtin_amdgcn_mfma_f32_16x16x32_bf16(a[m], bfr, accg[m][n], 0, 0, 0);
            }
        }
    }
    f32x4 acc[4][4] = {};
    for (int ks = 0; ks < 8; ++ks) {
        short8 a[4];
        #pragma unroll
        for (int m = 0; m < 4; ++m)
            a[m] = *reinterpret_cast<const short8*>((const char*)sE + swz512(m * 16 + lo, ks * 64 + hi * 16));
        #pragma unroll
        for (int n = 0; n < 4; ++n) {
            short8 bfr = *reinterpret_cast<const short8*>(&Wp1[(((size_t)ks * 16 + (w * 4 + n)) * 64 + l) * 8]);
            #pragma unroll
            for (int m = 0; m < 4; ++m)
                acc[m][n] = __builtin_amdgcn_mfma_f32_16x16x32_bf16(a[m], bfr, acc[m][n], 0, 0, 0);
        }
    }
    __syncthreads();

    // ---- phase D: gelu + write H (sH) and HG (alias over sE) ----
    {
        #pragma unroll
        for (int n = 0; n < 4; ++n) {
            int col = w * 64 + n * 16 + lo;
            float b1v = dih_b1[col];
            #pragma unroll
            for (int m = 0; m < 4; ++m) {
                int row0 = m * 16 + hi * 4;
                #pragma unroll
                for (int r = 0; r < 4; ++r) {
                    *reinterpret_cast<unsigned short*>((char*)sH + swz512(row0 + r, col * 2)) =
                        f2bf(gelu_fast(acc[m][n][r] + b1v));
                }
            }
        }
        unsigned short* sGH = sE;   // sE dead
        #pragma unroll
        for (int n = 0; n < 2; ++n) {
            int col = w * 32 + n * 16 + lo;
            float b1v = gbf_b1[col];
            #pragma unroll
            for (int m = 0; m < 4; ++m) {
                int row0 = m * 16 + hi * 4;
                #pragma unroll
                for (int r = 0; r < 4; ++r) {
                    *reinterpret_cast<unsigned short*>((char*)sGH + swz256(row0 + r, col * 2)) =
                        f2bf(gelu_fast(accg[m][n][r] + b1v));
                }
            }
        }
    }
    __syncthreads();

    // ---- phase E: GEMM2-dih + GEMM2-gbf + epilogue ----
    f32x4 acc2d[2] = {};
    for (int ks = 0; ks < 8; ++ks) {
        short8 a = *reinterpret_cast<const short8*>((const char*)sH + swz512(w * 16 + lo, ks * 64 + hi * 16));
        #pragma unroll
        for (int n = 0; n < 2; ++n) {
            short8 bfr = *reinterpret_cast<const short8*>(&Wp2[(((size_t)ks * 2 + n) * 64 + l) * 8]);
            acc2d[n] = __builtin_amdgcn_mfma_f32_16x16x32_bf16(a, bfr, acc2d[n], 0, 0, 0);
        }
    }
    f32x4 acc2g[2] = {};
    {
        const unsigned short* sGH = sE;
        for (int ks = 0; ks < 4; ++ks) {
            short8 a = *reinterpret_cast<const short8*>((const char*)sGH + swz256(w * 16 + lo, ks * 64 + hi * 16));
            #pragma unroll
            for (int n = 0; n < 2; ++n) {
                short8 bfr = *reinterpret_cast<const short8*>(&Wg2[(((size_t)ks * 2 + n) * 64 + l) * 8]);
                acc2g[n] = __builtin_amdgcn_mfma_f32_16x16x32_bf16(a, bfr, acc2g[n], 0, 0, 0);
            }
        }
    }

    float npos = no_pos[b];
    int e0 = w * 16 + hi * 4;
    #pragma unroll
    for (int n = 0; n < 2; ++n) {
        int h = n * 16 + lo;
        float bsum = dih_b2[h] + gbf_b2[h];
        float4 v;
        float vr;
        vr = (acc2d[n][0] + acc2g[n][0] + bsum) * npos; v.x = (skeep[e0 + 0] == 0.0f) ? -INFINITY : vr;
        vr = (acc2d[n][1] + acc2g[n][1] + bsum) * npos; v.y = (skeep[e0 + 1] == 0.0f) ? -INFINITY : vr;
        vr = (acc2d[n][2] + acc2g[n][2] + bsum) * npos; v.z = (skeep[e0 + 2] == 0.0f) ? -INFINITY : vr;
        vr = (acc2d[n][3] + acc2g[n][3] + bsum) * npos; v.w = (skeep[e0 + 3] == 0.0f) ? -INFINITY : vr;
        *reinterpret_cast<float4*>(&out_attn[(((size_t)b * HH + h) * NN + i) * NN + j0 + e0]) = v;
    }
}

extern "C" void kernel_launch(void* const* d_in, const int* in_sizes, int n_in,
                              void* d_out, int out_size, void* d_ws, size_t ws_size,
                              hipStream_t stream) {
    const float* pos       = (const float*)d_in[0];
    const float* atom_emb  = (const float*)d_in[1];
    const float* W_la      = (const float*)d_in[2];
    const float* W_ra      = (const float*)d_in[3];
    const float* W_ld      = (const float*)d_in[4];
    const float* W_rd      = (const float*)d_in[5];
    const float* gbf_means = (const float*)d_in[6];
    const float* gbf_stds  = (const float*)d_in[7];
    const float* src_mul   = (const float*)d_in[8];
    const float* tgt_mul   = (const float*)d_in[9];
    const float* src_bias  = (const float*)d_in[10];
    const float* tgt_bias  = (const float*)d_in[11];
    const float* gbf_W1    = (const float*)d_in[12];
    const float* gbf_b1    = (const float*)d_in[13];
    const float* gbf_W2    = (const float*)d_in[14];
    const float* gbf_b2    = (const float*)d_in[15];
    const float* dih_W1    = (const float*)d_in[16];
    const float* dih_b1    = (const float*)d_in[17];
    const float* dih_W2    = (const float*)d_in[18];
    const float* dih_b2    = (const float*)d_in[19];
    const float* ang_W1    = (const float*)d_in[20];
    const float* ang_b1    = (const float*)d_in[21];
    const float* ang_W2    = (const float*)d_in[22];
    const float* ang_b2    = (const float*)d_in[23];
    const int*   x         = (const int*)d_in[24];
    const int*   nte       = (const int*)d_in[25];

    float* out = (float*)d_out;
    float* out_attn  = out;                                  // [4,32,128,128]
    float* out_angle = out + (size_t)BB * HH * NN * NN;      // [4,128,256]
    float* out_dp    = out_angle + (size_t)BB * NN * DD;     // [4,128,128,3]

    float* ws = (float*)d_ws;
    float* keep    = ws;                       // 512
    float* no_pos  = ws + 512;                 // 4
    float* s_ws    = ws + 1024;                // 1536
    float* dist_ws = ws + 4096;                // 65536
    float* ld_ws   = ws + 4096 + 65536;        // 131072
    float* rd_ws   = ld_ws + (size_t)BB * NN * DD;   // 131072
    unsigned short* wp = (unsigned short*)(ws + 331776);
    unsigned short* Wp1    = wp;                 // 65536
    unsigned short* Wp2    = wp + 65536;         // 8192
    unsigned short* Wg1    = wp + 73728;         // 16384
    unsigned short* Wg2    = wp + 90112;         // 4096
    unsigned short* Wla_p  = wp + 94208;         // 65536
    unsigned short* Wra_p  = wp + 159744;        // 65536
    unsigned short* Wld_p  = wp + 225280;        // 65536
    unsigned short* Wrd_p  = wp + 290816;        // 65536
    unsigned short* WaW1_p = wp + 356352;        // 65536
    unsigned short* WaW2_p = wp + 421888;        // 65536  -> ends at f32 offset 575488
    unsigned short* nf_ws  = (unsigned short*)(ws + 575488);   // 131072 ushorts
    unsigned short* ap_ws  = (unsigned short*)(ws + 641024);   // 131072 ushorts -> ~2.83 MB total

    k_setup<<<dim3(1262), dim3(256), 0, stream>>>(
        pos, x, atom_emb, dih_W1, dih_W2, gbf_W1, gbf_W2,
        W_la, W_ra, W_ld, W_rd, ang_W1, ang_W2,
        out_dp, dist_ws, s_ws, keep, no_pos, nf_ws, wp);
    k2a<<<dim3(64), dim3(256), 0, stream>>>(nf_ws, Wla_p, Wra_p, Wld_p, Wrd_p,
                                            s_ws, ld_ws, rd_ws, ap_ws);
    k_mega<<<dim3(16 + BB * NN * 2), dim3(256), 0, stream>>>(
        Wp1, Wp2, Wg1, Wg2, WaW1_p, WaW2_p,
        dih_b1, dih_b2, gbf_b1, gbf_b2, ang_b1, ang_b2,
        gbf_means, gbf_stds, src_mul, tgt_mul, src_bias, tgt_bias, nte,
        ap_ws, ld_ws, rd_ws, s_ws, dist_ws, keep, no_pos, out_dp,
        out_angle, out_attn);
}

// Round 11
// 148.341 us; speedup vs baseline: 2.6616x; 1.0081x over previous
//
#include <hip/hip_runtime.h>
#include <math.h>

#define BB 4
#define NN 128
#define DD 256
#define KK 128
#define HH 32
#define AA 128
#define EE 512

typedef float f32x4 __attribute__((ext_vector_type(4)));
typedef short short8 __attribute__((ext_vector_type(8)));

// tanh-form GELU: x * sigmoid(2*0.7978845608*(x + 0.044715 x^3)); |err| <= ~3e-4
__device__ __forceinline__ float gelu_fast(float x) {
    float x2 = x * x;
    float t = x * fmaf(x2, 0.0713548162726f, 1.59576912161f);
    float e = __expf(-t);
    return x * __builtin_amdgcn_rcpf(1.0f + e);
}

__device__ __forceinline__ unsigned short f2bf(float f) {
    unsigned int u = __float_as_uint(f);
    u = u + 0x7fffu + ((u >> 16) & 1u);
    return (unsigned short)(u >> 16);
}

// byte-offset swizzles (XOR row into 16B-slot bit) for bank-conflict-free ds_read_b128
__device__ __forceinline__ int swz512(int row, int colByte) {   // 512B row stride
    return row * 512 + (colByte ^ ((row & 7) << 4));
}
__device__ __forceinline__ int swz256(int row, int colByte) {   // 256B row stride
    return row * 256 + (colByte ^ ((row & 7) << 4));
}

// ================ K_setup: fused k1_geom (blk<512) + k_nf (blk<1024) + k_pack ================
__global__ __launch_bounds__(256) void k_setup(
    const float* __restrict__ pos, const int* __restrict__ x,
    const float* __restrict__ atom_emb,
    const float* __restrict__ dW1, const float* __restrict__ dW2,
    const float* __restrict__ gW1, const float* __restrict__ gW2,
    const float* __restrict__ wla, const float* __restrict__ wra,
    const float* __restrict__ wld, const float* __restrict__ wrd,
    const float* __restrict__ aW1, const float* __restrict__ aW2,
    float* __restrict__ out_dp, float* __restrict__ dist_ws,
    float* __restrict__ s_ws, float* __restrict__ keep, float* __restrict__ no_pos,
    unsigned short* __restrict__ nf_ws, unsigned short* __restrict__ wpack) {
    int blk = blockIdx.x;
    int t = threadIdx.x;

    if (blk < 512) {
        int bi = blk;
        int b = bi >> 7;
        int i = bi & 127;
        __shared__ float red[3][128];
        __shared__ int flag;
        if (t == 0) flag = 0;
        float kj = 0.0f, dx = 0.0f, dy = 0.0f, dz = 0.0f;
        float pjx = 0.0f, pjy = 0.0f, pjz = 0.0f;
        int bj = b * NN + (t & 127);
        if (t < 128) {
            int j = t;
            int allz = 1;
            #pragma unroll
            for (int f = 0; f < 9; ++f) allz &= (x[bj * 9 + f] == 0);
            kj = allz ? 0.0f : 1.0f;
            float pix = pos[bi * 3 + 0], piy = pos[bi * 3 + 1], piz = pos[bi * 3 + 2];
            pjx = pos[bj * 3 + 0]; pjy = pos[bj * 3 + 1]; pjz = pos[bj * 3 + 2];
            dx = pjx - pix; dy = pjy - piy; dz = pjz - piz;
            float dist = sqrtf(dx * dx + dy * dy + dz * dz);
            float inv = 1.0f / (dist + 1e-5f);
            dx *= inv; dy *= inv; dz *= inv;
            size_t e = (size_t)bi * NN + j;
            out_dp[e * 3 + 0] = dx;
            out_dp[e * 3 + 1] = dy;
            out_dp[e * 3 + 2] = dz;
            dist_ws[e] = dist;
            red[0][j] = kj * dx; red[1][j] = kj * dy; red[2][j] = kj * dz;
        }
        __syncthreads();
        if (t < 128) {
            if (pjx != 0.0f || pjy != 0.0f || pjz != 0.0f) flag = 1;
        }
        for (int off = 64; off > 0; off >>= 1) {
            if (t < off) {
                red[0][t] += red[0][t + off];
                red[1][t] += red[1][t + off];
                red[2][t] += red[2][t + off];
            }
            __syncthreads();
        }
        if (t == 0) {
            s_ws[bi * 3 + 0] = red[0][0];
            s_ws[bi * 3 + 1] = red[1][0];
            s_ws[bi * 3 + 2] = red[2][0];
        }
        if (i == 0 && t < 128) {
            keep[bj] = kj;
            if (t == 0) no_pos[b] = flag ? 1.0f : 0.0f;
        }
        return;
    }

    if (blk < 1024) {
        int bn = blk - 512;
        float acc = 0.0f;
        #pragma unroll
        for (int f = 0; f < 9; ++f) {
            int xi = x[bn * 9 + f];
            acc += atom_emb[((size_t)(f * (AA + 1) + xi)) * DD + t];
        }
        nf_ws[(size_t)bn * DD + t] = f2bf(acc);
        return;
    }

    // ---- k_pack role ----
    {
        int idx = (blk - 1024) * 256 + t;   // 0..60927
        const float* W; int Nc, base, k, c8;
        if (idx < 8192)       { W = dW1; Nc = 256; base = 0;     int li = idx;         k = li >> 5; c8 = li & 31; }
        else if (idx < 9216)  { W = dW2; Nc = 32;  base = 65536; int li = idx - 8192;  k = li >> 2; c8 = li & 3; }
        else if (idx < 11264) { W = gW1; Nc = 128; base = 73728; int li = idx - 9216;  k = li >> 4; c8 = li & 15; }
        else if (idx < 11776) { W = gW2; Nc = 32;  base = 90112; int li = idx - 11264; k = li >> 2; c8 = li & 3; }
        else if (idx < 60928) {
            int q  = (idx - 11776) >> 13;        // 0..5
            int li = (idx - 11776) & 8191;
            W = (q == 0) ? wla : (q == 1) ? wra : (q == 2) ? wld : (q == 3) ? wrd : (q == 4) ? aW1 : aW2;
            Nc = 256; base = 94208 + q * 65536; k = li >> 5; c8 = li & 31;
        }
        else return;
        int ntiles = Nc >> 4;
        int ks = k >> 5, hi = (k & 31) >> 3, ee = k & 7;
        const float* wp = &W[k * Nc + c8 * 8];
        float4 a = *reinterpret_cast<const float4*>(wp);
        float4 b4 = *reinterpret_cast<const float4*>(wp + 4);
        float vals[8] = {a.x, a.y, a.z, a.w, b4.x, b4.y, b4.z, b4.w};
        #pragma unroll
        for (int jj = 0; jj < 8; ++jj) {
            int c = c8 * 8 + jj;
            int nt = c >> 4, lo = c & 15;
            wpack[base + (((ks * ntiles + nt) * 64) + hi * 16 + lo) * 8 + ee] = f2bf(vals[jj]);
        }
    }
}

// ---- stage a 32x256 bf16 row-major buffer into swizzled LDS (4 short8/thread) ----
__device__ __forceinline__ void stage32x256(const unsigned short* __restrict__ src, int bn0,
                                            unsigned short* sA, int t) {
    #pragma unroll
    for (int r = 0; r < 4; ++r) {
        int idx = r * 256 + t;
        int row = idx >> 5;
        int c8 = idx & 31;
        short8 v = *reinterpret_cast<const short8*>(&src[((size_t)(bn0 + row)) * DD + c8 * 8]);
        *reinterpret_cast<short8*>((char*)sA + swz512(row, c8 * 16)) = v;
    }
}

// ---- [32 x 256] @ B-chunk(16 cols, n-tile nt) -> acc[2] ----
__device__ __forceinline__ void gemm_nt(const unsigned short* __restrict__ Bp, int nt,
                                        const unsigned short* sA, int l, int lo, int hi,
                                        f32x4 acc[2]) {
    for (int ks = 0; ks < 8; ++ks) {
        short8 a0 = *reinterpret_cast<const short8*>((const char*)sA + swz512(lo, ks * 64 + hi * 16));
        short8 a1 = *reinterpret_cast<const short8*>((const char*)sA + swz512(16 + lo, ks * 64 + hi * 16));
        short8 bfr = *reinterpret_cast<const short8*>(&Bp[(((size_t)ks * 16 + nt) * 64 + l) * 8]);
        acc[0] = __builtin_amdgcn_mfma_f32_16x16x32_bf16(a0, bfr, acc[0], 0, 0, 0);
        acc[1] = __builtin_amdgcn_mfma_f32_16x16x32_bf16(a1, bfr, acc[1], 0, 0, 0);
    }
}

// ---- [32 x 256] @ [256 x 256] chunk GEMM, wave w owns cols w*64..w*64+63 ----
__device__ __forceinline__ void gemm_chunk32(const unsigned short* __restrict__ Bp,
                                             const unsigned short* sAp,
                                             int w, int l, int lo, int hi,
                                             f32x4 acc[2][4]) {
    for (int ks = 0; ks < 8; ++ks) {
        short8 a[2];
        #pragma unroll
        for (int m = 0; m < 2; ++m)
            a[m] = *reinterpret_cast<const short8*>((const char*)sAp + swz512(m * 16 + lo, ks * 64 + hi * 16));
        #pragma unroll
        for (int n = 0; n < 4; ++n) {
            short8 bfr = *reinterpret_cast<const short8*>(&Bp[(((size_t)ks * 16 + (w * 4 + n)) * 64 + l) * 8]);
            #pragma unroll
            for (int m = 0; m < 2; ++m)
                acc[m][n] = __builtin_amdgcn_mfma_f32_16x16x32_bf16(a[m], bfr, acc[m][n], 0, 0, 0);
        }
    }
}

// ================ K2a: 256 blocks = 16 tiles x 16 n-tiles; wave w -> matrix w ================
__global__ __launch_bounds__(256, 4) void k2a(
    const unsigned short* __restrict__ nf_ws,
    const unsigned short* __restrict__ Wla_p, const unsigned short* __restrict__ Wra_p,
    const unsigned short* __restrict__ Wld_p, const unsigned short* __restrict__ Wrd_p,
    const float* __restrict__ s_ws,
    float* __restrict__ ld_ws, float* __restrict__ rd_ws,
    unsigned short* __restrict__ ap_ws) {
    int blk = blockIdx.x;
    int nt = blk & 15, tile = blk >> 4;
    int bn0 = tile * 32;
    int t = threadIdx.x;
    int w = t >> 6, l = t & 63, lo = l & 15, hi = l >> 4;

    __shared__ __align__(16) unsigned short sA[32 * 256];
    __shared__ float sLA[32][16];
    __shared__ float sRA[32][16];
    __shared__ float ls2[32];
    if (t < 32) {
        float a0 = s_ws[(bn0 + t) * 3 + 0];
        float a1 = s_ws[(bn0 + t) * 3 + 1];
        float a2 = s_ws[(bn0 + t) * 3 + 2];
        ls2[t] = a0 * a0 + a1 * a1 + a2 * a2;
    }
    stage32x256(nf_ws, bn0, sA, t);
    __syncthreads();

    const unsigned short* Bp = (w == 0) ? Wla_p : (w == 1) ? Wra_p : (w == 2) ? Wld_p : Wrd_p;
    f32x4 acc[2] = {};
    gemm_nt(Bp, nt, sA, l, lo, hi, acc);

    int col = nt * 16 + lo;
    if (w == 0 || w == 1) {
        float (*dst)[16] = (w == 0) ? sLA : sRA;
        #pragma unroll
        for (int m = 0; m < 2; ++m)
            #pragma unroll
            for (int r = 0; r < 4; ++r)
                dst[m * 16 + hi * 4 + r][lo] = acc[m][r];
    } else {
        float* dstg = (w == 2) ? ld_ws : rd_ws;
        #pragma unroll
        for (int m = 0; m < 2; ++m)
            #pragma unroll
            for (int r = 0; r < 4; ++r)
                dstg[(size_t)(bn0 + m * 16 + hi * 4 + r) * DD + col] = acc[m][r];
    }
    __syncthreads();

    if (w == 0) {
        #pragma unroll
        for (int r8 = 0; r8 < 8; ++r8) {
            int row = hi * 8 + r8;
            ap_ws[(size_t)(bn0 + row) * DD + nt * 16 + lo] =
                f2bf(ls2[row] * sLA[row][lo] * sRA[row][lo]);
        }
    }
}

// ================ K_mega: blocks 0..15 = angle MLP (k2bc); blocks 16+ = edge kernel (k3) ================
// LDS: sE 32KB (E full / k2bc sA+HG), sH2 16KB (G -> H halves / k2bc sB) -> 3 blocks/CU
__global__ __launch_bounds__(256, 3) void k_mega(
    const unsigned short* __restrict__ Wp1, const unsigned short* __restrict__ Wp2,
    const unsigned short* __restrict__ Wg1, const unsigned short* __restrict__ Wg2,
    const unsigned short* __restrict__ WaW1_p, const unsigned short* __restrict__ WaW2_p,
    const float* __restrict__ dih_b1, const float* __restrict__ dih_b2,
    const float* __restrict__ gbf_b1, const float* __restrict__ gbf_b2,
    const float* __restrict__ ang_b1, const float* __restrict__ ang_b2,
    const float* __restrict__ gbf_means, const float* __restrict__ gbf_stds,
    const float* __restrict__ src_mul, const float* __restrict__ tgt_mul,
    const float* __restrict__ src_bias, const float* __restrict__ tgt_bias,
    const int* __restrict__ nte,
    const unsigned short* __restrict__ ap_ws,
    const float* __restrict__ ld_ws, const float* __restrict__ rd_ws,
    const float* __restrict__ s_ws, const float* __restrict__ dist_ws,
    const float* __restrict__ keep, const float* __restrict__ no_pos,
    const float* __restrict__ dp_in,
    float* __restrict__ out_angle, float* __restrict__ out_attn) {
    int t = threadIdx.x;
    int w  = t >> 6;
    int l  = t & 63;
    int lo = l & 15;
    int hi = l >> 4;

    __shared__ __align__(16) unsigned short sE[64 * 256];   // 32 KB
    __shared__ __align__(16) unsigned short sH2[64 * 128];  // 16 KB
    __shared__ __align__(16) float rd_l[DD];
    __shared__ float sg[64], sxg[64], skeep[64];
    __shared__ __align__(16) float lmean[KK], linv[KK], lcoef[KK];

    if (blockIdx.x < 16) {
        // ======== k2bc role: full-width angle MLP for 32-node tile ========
        int tile = blockIdx.x;
        int bn0 = tile * 32;
        stage32x256(ap_ws, bn0, sE, t);
        __syncthreads();
        {
            f32x4 acc[2][4] = {};
            gemm_chunk32(WaW1_p, sE, w, l, lo, hi, acc);
            #pragma unroll
            for (int n = 0; n < 4; ++n) {
                int col = w * 64 + n * 16 + lo;
                float b1v = ang_b1[col];
                #pragma unroll
                for (int m = 0; m < 2; ++m)
                    #pragma unroll
                    for (int r = 0; r < 4; ++r) {
                        int row = m * 16 + hi * 4 + r;
                        *reinterpret_cast<unsigned short*>((char*)sH2 + swz512(row, col * 2)) =
                            f2bf(gelu_fast(acc[m][n][r] + b1v));
                    }
            }
        }
        __syncthreads();
        {
            f32x4 acc[2][4] = {};
            gemm_chunk32(WaW2_p, sH2, w, l, lo, hi, acc);
            float lnp = no_pos[tile >> 2];
            #pragma unroll
            for (int n = 0; n < 4; ++n) {
                int col = w * 64 + n * 16 + lo;
                float b2v = ang_b2[col];
                #pragma unroll
                for (int m = 0; m < 2; ++m)
                    #pragma unroll
                    for (int r = 0; r < 4; ++r) {
                        int row = m * 16 + hi * 4 + r;
                        out_angle[(size_t)(bn0 + row) * DD + col] = (acc[m][n][r] + b2v) * lnp;
                    }
            }
        }
        return;
    }

    // ======== k3 role: edge kernel, 64 edges/block ========
    int blk = blockIdx.x - 16;
    int jh = blk & 1;
    int i  = (blk >> 1) & 127;
    int b  = blk >> 8;
    int j0 = jh * 64;

    int bi = b * NN + i;

    // ---- phase A: per-edge scalars + rd row + gaussian constants ----
    if (t < 64) {
        int j = j0 + t;
        size_t e = (size_t)bi * NN + j;
        float d0 = dp_in[e * 3 + 0], d1 = dp_in[e * 3 + 1], d2 = dp_in[e * 3 + 2];
        float si0 = s_ws[bi * 3 + 0], si1 = s_ws[bi * 3 + 1], si2 = s_ws[bi * 3 + 2];
        int bj = b * NN + j;
        float sj0 = s_ws[bj * 3 + 0], sj1 = s_ws[bj * 3 + 1], sj2 = s_ws[bj * 3 + 2];
        float u = sj0 * d0 + sj1 * d1 + sj2 * d2;
        float v = si0 * d0 + si1 * d1 + si2 * d2;
        float dp2 = d0 * d0 + d1 * d1 + d2 * d2;
        sg[t] = (si0 * sj0 + si1 * sj1 + si2 * sj2) - u * v * (2.0f - dp2);
        int et0 = nte[e * 2 + 0], et1 = nte[e * 2 + 1];
        sxg[t] = (src_mul[et0] + tgt_mul[et1]) * dist_ws[e] + src_bias[et0] + tgt_bias[et1];
        skeep[t] = keep[bj];
    } else if (t < 128) {
        int q = t - 64;
        reinterpret_cast<float4*>(rd_l)[q] =
            reinterpret_cast<const float4*>(&rd_ws[(size_t)bi * DD])[q];
    } else {
        int k = t - 128;
        float s = fabsf(gbf_stds[k]) + 0.01f;
        lmean[k] = gbf_means[k];
        linv[k] = 1.0f / s;
        lcoef[k] = 1.0f / (2.5066262f * s);
    }
    __syncthreads();

    // ---- phase B: build E full (sE, swz512) and G (sH2, swz256) ----
    {
        const float* ldbase = &ld_ws[((size_t)(b * NN + j0)) * DD];
        #pragma unroll
        for (int r = 0; r < 8; ++r) {
            int idx = r * 256 + t;
            int row = idx >> 5;
            int c8  = idx & 31;
            float g = sg[row];
            const float* lp = ldbase + row * DD + c8 * 8;
            float4 l0 = *reinterpret_cast<const float4*>(lp);
            float4 l1 = *reinterpret_cast<const float4*>(lp + 4);
            float4 r0 = *reinterpret_cast<const float4*>(&rd_l[c8 * 8]);
            float4 r1 = *reinterpret_cast<const float4*>(&rd_l[c8 * 8 + 4]);
            short8 vv;
            vv[0] = (short)f2bf(g * l0.x * r0.x);
            vv[1] = (short)f2bf(g * l0.y * r0.y);
            vv[2] = (short)f2bf(g * l0.z * r0.z);
            vv[3] = (short)f2bf(g * l0.w * r0.w);
            vv[4] = (short)f2bf(g * l1.x * r1.x);
            vv[5] = (short)f2bf(g * l1.y * r1.y);
            vv[6] = (short)f2bf(g * l1.z * r1.z);
            vv[7] = (short)f2bf(g * l1.w * r1.w);
            *reinterpret_cast<short8*>((char*)sE + swz512(row, c8 * 16)) = vv;
        }
        #pragma unroll
        for (int r = 0; r < 4; ++r) {
            int idx = r * 256 + t;
            int row = idx >> 4;
            int c8  = idx & 15;
            float xv = sxg[row];
            float4 m0 = *reinterpret_cast<const float4*>(&lmean[c8 * 8]);
            float4 m1 = *reinterpret_cast<const float4*>(&lmean[c8 * 8 + 4]);
            float4 i0 = *reinterpret_cast<const float4*>(&linv[c8 * 8]);
            float4 i1 = *reinterpret_cast<const float4*>(&linv[c8 * 8 + 4]);
            float4 c0 = *reinterpret_cast<const float4*>(&lcoef[c8 * 8]);
            float4 c1 = *reinterpret_cast<const float4*>(&lcoef[c8 * 8 + 4]);
            float z;
            short8 vv;
            z = (xv - m0.x) * i0.x; vv[0] = (short)f2bf(c0.x * __expf(-0.5f * z * z));
            z = (xv - m0.y) * i0.y; vv[1] = (short)f2bf(c0.y * __expf(-0.5f * z * z));
            z = (xv - m0.z) * i0.z; vv[2] = (short)f2bf(c0.z * __expf(-0.5f * z * z));
            z = (xv - m0.w) * i0.w; vv[3] = (short)f2bf(c0.w * __expf(-0.5f * z * z));
            z = (xv - m1.x) * i1.x; vv[4] = (short)f2bf(c1.x * __expf(-0.5f * z * z));
            z = (xv - m1.y) * i1.y; vv[5] = (short)f2bf(c1.y * __expf(-0.5f * z * z));
            z = (xv - m1.z) * i1.z; vv[6] = (short)f2bf(c1.z * __expf(-0.5f * z * z));
            z = (xv - m1.w) * i1.w; vv[7] = (short)f2bf(c1.w * __expf(-0.5f * z * z));
            *reinterpret_cast<short8*>((char*)sH2 + swz256(row, c8 * 16)) = vv;
        }
    }
    __syncthreads();

    // ---- phase C: GEMM1-gbf (reads sH2=G) and GEMM1-dih (reads sE, full K) ----
    f32x4 accg[4][2] = {};
    for (int ks = 0; ks < 4; ++ks) {
        short8 a[4];
        #pragma unroll
        for (int m = 0; m < 4; ++m)
            a[m] = *reinterpret_cast<const short8*>((const char*)sH2 + swz256(m * 16 + lo, ks * 64 + hi * 16));
        #pragma unroll
        for (int n = 0; n < 2; ++n) {
            short8 bfr = *reinterpret_cast<const short8*>(&Wg1[(((size_t)ks * 8 + (w * 2 + n)) * 64 + l) * 8]);
            #pragma unroll
            for (int m = 0; m < 4; ++m)
                accg[m][n] = __builtin_amdgcn_mfma_f32_16x16x32_bf16(a[m], bfr, accg[m][n], 0, 0, 0);
        }
    }
    f32x4 acc[4][4] = {};
    for (int ks = 0; ks < 8; ++ks) {
        short8 a[4];
        #pragma unroll
        for (int m = 0; m < 4; ++m)
            a[m] = *reinterpret_cast<const short8*>((const char*)sE + swz512(m * 16 + lo, ks * 64 + hi * 16));
        #pragma unroll
        for (int n = 0; n < 4; ++n) {
            short8 bfr = *reinterpret_cast<const short8*>(&Wp1[(((size_t)ks * 16 + (w * 4 + n)) * 64 + l) * 8]);
            #pragma unroll
            for (int m = 0; m < 4; ++m)
                acc[m][n] = __builtin_amdgcn_mfma_f32_16x16x32_bf16(a[m], bfr, acc[m][n], 0, 0, 0);
        }
    }
    __syncthreads();   // E and G fully consumed

    // ---- phase D0: HG -> sE (swz256); H cols 0..127 (waves 0,1) -> sH2 (swz256) ----
    {
        unsigned short* sGH = sE;
        #pragma unroll
        for (int n = 0; n < 2; ++n) {
            int col = w * 32 + n * 16 + lo;
            float b1v = gbf_b1[col];
            #pragma unroll
            for (int m = 0; m < 4; ++m) {
                int row0 = m * 16 + hi * 4;
                #pragma unroll
                for (int r = 0; r < 4; ++r) {
                    *reinterpret_cast<unsigned short*>((char*)sGH + swz256(row0 + r, col * 2)) =
                        f2bf(gelu_fast(accg[m][n][r] + b1v));
                }
            }
        }
        if (w < 2) {
            #pragma unroll
            for (int n = 0; n < 4; ++n) {
                int col = w * 64 + n * 16 + lo;       // 0..127
                float b1v = dih_b1[col];
                #pragma unroll
                for (int m = 0; m < 4; ++m) {
                    int row0 = m * 16 + hi * 4;
                    #pragma unroll
                    for (int r = 0; r < 4; ++r) {
                        *reinterpret_cast<unsigned short*>((char*)sH2 + swz256(row0 + r, col * 2)) =
                            f2bf(gelu_fast(acc[m][n][r] + b1v));
                    }
                }
            }
        }
    }
    __syncthreads();

    // ---- phase E0: GEMM2-gbf (reads sE=HG) + GEMM2-dih ks 0..3 (reads sH2=H half0) ----
    f32x4 acc2g[2] = {};
    {
        const unsigned short* sGH = sE;
        for (int ks = 0; ks < 4; ++ks) {
            short8 a = *reinterpret_cast<const short8*>((const char*)sGH + swz256(w * 16 + lo, ks * 64 + hi * 16));
            #pragma unroll
            for (int n = 0; n < 2; ++n) {
                short8 bfr = *reinterpret_cast<const short8*>(&Wg2[(((size_t)ks * 2 + n) * 64 + l) * 8]);
                acc2g[n] = __builtin_amdgcn_mfma_f32_16x16x32_bf16(a, bfr, acc2g[n], 0, 0, 0);
            }
        }
    }
    f32x4 acc2d[2] = {};
    for (int ks = 0; ks < 4; ++ks) {
        short8 a = *reinterpret_cast<const short8*>((const char*)sH2 + swz256(w * 16 + lo, ks * 64 + hi * 16));
        #pragma unroll
        for (int n = 0; n < 2; ++n) {
            short8 bfr = *reinterpret_cast<const short8*>(&Wp2[(((size_t)ks * 2 + n) * 64 + l) * 8]);
            acc2d[n] = __builtin_amdgcn_mfma_f32_16x16x32_bf16(a, bfr, acc2d[n], 0, 0, 0);
        }
    }
    __syncthreads();   // H half0 consumed

    // ---- phase D1: H cols 128..255 (waves 2,3) -> sH2 ----
    if (w >= 2) {
        #pragma unroll
        for (int n = 0; n < 4; ++n) {
            int col = w * 64 + n * 16 + lo;           // 128..255
            float b1v = dih_b1[col];
            int hcol = col - 128;
            #pragma unroll
            for (int m = 0; m < 4; ++m) {
                int row0 = m * 16 + hi * 4;
                #pragma unroll
                for (int r = 0; r < 4; ++r) {
                    *reinterpret_cast<unsigned short*>((char*)sH2 + swz256(row0 + r, hcol * 2)) =
                        f2bf(gelu_fast(acc[m][n][r] + b1v));
                }
            }
        }
    }
    __syncthreads();

    // ---- phase E1: GEMM2-dih ks 4..7 + epilogue ----
    for (int ks = 0; ks < 4; ++ks) {
        short8 a = *reinterpret_cast<const short8*>((const char*)sH2 + swz256(w * 16 + lo, ks * 64 + hi * 16));
        #pragma unroll
        for (int n = 0; n < 2; ++n) {
            short8 bfr = *reinterpret_cast<const short8*>(&Wp2[(((size_t)(ks + 4) * 2 + n) * 64 + l) * 8]);
            acc2d[n] = __builtin_amdgcn_mfma_f32_16x16x32_bf16(a, bfr, acc2d[n], 0, 0, 0);
        }
    }

    float npos = no_pos[b];
    int e0 = w * 16 + hi * 4;
    #pragma unroll
    for (int n = 0; n < 2; ++n) {
        int h = n * 16 + lo;
        float bsum = dih_b2[h] + gbf_b2[h];
        float4 v;
        float vr;
        vr = (acc2d[n][0] + acc2g[n][0] + bsum) * npos; v.x = (skeep[e0 + 0] == 0.0f) ? -INFINITY : vr;
        vr = (acc2d[n][1] + acc2g[n][1] + bsum) * npos; v.y = (skeep[e0 + 1] == 0.0f) ? -INFINITY : vr;
        vr = (acc2d[n][2] + acc2g[n][2] + bsum) * npos; v.z = (skeep[e0 + 2] == 0.0f) ? -INFINITY : vr;
        vr = (acc2d[n][3] + acc2g[n][3] + bsum) * npos; v.w = (skeep[e0 + 3] == 0.0f) ? -INFINITY : vr;
        *reinterpret_cast<float4*>(&out_attn[(((size_t)b * HH + h) * NN + i) * NN + j0 + e0]) = v;
    }
}

extern "C" void kernel_launch(void* const* d_in, const int* in_sizes, int n_in,
                              void* d_out, int out_size, void* d_ws, size_t ws_size,
                              hipStream_t stream) {
    const float* pos       = (const float*)d_in[0];
    const float* atom_emb  = (const float*)d_in[1];
    const float* W_la      = (const float*)d_in[2];
    const float* W_ra      = (const float*)d_in[3];
    const float* W_ld      = (const float*)d_in[4];
    const float* W_rd      = (const float*)d_in[5];
    const float* gbf_means = (const float*)d_in[6];
    const float* gbf_stds  = (const float*)d_in[7];
    const float* src_mul   = (const float*)d_in[8];
    const float* tgt_mul   = (const float*)d_in[9];
    const float* src_bias  = (const float*)d_in[10];
    const float* tgt_bias  = (const float*)d_in[11];
    const float* gbf_W1    = (const float*)d_in[12];
    const float* gbf_b1    = (const float*)d_in[13];
    const float* gbf_W2    = (const float*)d_in[14];
    const float* gbf_b2    = (const float*)d_in[15];
    const float* dih_W1    = (const float*)d_in[16];
    const float* dih_b1    = (const float*)d_in[17];
    const float* dih_W2    = (const float*)d_in[18];
    const float* dih_b2    = (const float*)d_in[19];
    const float* ang_W1    = (const float*)d_in[20];
    const float* ang_b1    = (const float*)d_in[21];
    const float* ang_W2    = (const float*)d_in[22];
    const float* ang_b2    = (const float*)d_in[23];
    const int*   x         = (const int*)d_in[24];
    const int*   nte       = (const int*)d_in[25];

    float* out = (float*)d_out;
    float* out_attn  = out;                                  // [4,32,128,128]
    float* out_angle = out + (size_t)BB * HH * NN * NN;      // [4,128,256]
    float* out_dp    = out_angle + (size_t)BB * NN * DD;     // [4,128,128,3]

    float* ws = (float*)d_ws;
    float* keep    = ws;                       // 512
    float* no_pos  = ws + 512;                 // 4
    float* s_ws    = ws + 1024;                // 1536
    float* dist_ws = ws + 4096;                // 65536
    float* ld_ws   = ws + 4096 + 65536;        // 131072
    float* rd_ws   = ld_ws + (size_t)BB * NN * DD;   // 131072
    unsigned short* wp = (unsigned short*)(ws + 331776);
    unsigned short* Wp1    = wp;                 // 65536
    unsigned short* Wp2    = wp + 65536;         // 8192
    unsigned short* Wg1    = wp + 73728;         // 16384
    unsigned short* Wg2    = wp + 90112;         // 4096
    unsigned short* Wla_p  = wp + 94208;         // 65536
    unsigned short* Wra_p  = wp + 159744;        // 65536
    unsigned short* Wld_p  = wp + 225280;        // 65536
    unsigned short* Wrd_p  = wp + 290816;        // 65536
    unsigned short* WaW1_p = wp + 356352;        // 65536
    unsigned short* WaW2_p = wp + 421888;        // 65536  -> ends at f32 offset 575488
    unsigned short* nf_ws  = (unsigned short*)(ws + 575488);   // 131072 ushorts
    unsigned short* ap_ws  = (unsigned short*)(ws + 641024);   // 131072 ushorts -> ~2.83 MB total

    k_setup<<<dim3(1262), dim3(256), 0, stream>>>(
        pos, x, atom_emb, dih_W1, dih_W2, gbf_W1, gbf_W2,
        W_la, W_ra, W_ld, W_rd, ang_W1, ang_W2,
        out_dp, dist_ws, s_ws, keep, no_pos, nf_ws, wp);
    k2a<<<dim3(256), dim3(256), 0, stream>>>(nf_ws, Wla_p, Wra_p, Wld_p, Wrd_p,
                                             s_ws, ld_ws, rd_ws, ap_ws);
    k_mega<<<dim3(16 + BB * NN * 2), dim3(256), 0, stream>>>(
        Wp1, Wp2, Wg1, Wg2, WaW1_p, WaW2_p,
        dih_b1, dih_b2, gbf_b1, gbf_b2, ang_b1, ang_b2,
        gbf_means, gbf_stds, src_mul, tgt_mul, src_bias, tgt_bias, nte,
        ap_ws, ld_ws, rd_ws, s_ws, dist_ws, keep, no_pos, out_dp,
        out_angle, out_attn);
}